// Round 4
// baseline (216.422 us; speedup 1.0000x reference)
//
#include <hip/hip_runtime.h>
#include <hip/hip_bf16.h>
#include <math.h>

// ---------------- constants ----------------
#define HDIM 128
#define SCAN_B 256
#define NBLK 256          // edge blocks for hist/scatter passes

typedef short bfrag __attribute__((ext_vector_type(8)));   // 8 bf16 (4 VGPRs)
typedef float f32x4 __attribute__((ext_vector_type(4)));   // 4 fp32 acc

__device__ inline unsigned short f2bf_rne(float x) {
    unsigned u = __float_as_uint(x);
    u = (u + 0x7fffu + ((u >> 16) & 1u)) >> 16;
    return (unsigned short)u;
}
__device__ inline float bf_lo(unsigned u) { return __uint_as_float(u << 16); }
__device__ inline float bf_hi(unsigned u) { return __uint_as_float(u & 0xffff0000u); }

// ---------------- device bodies ----------------

// Pass A: per-block LDS coarse histogram (dst>>8); no global atomics.
__device__ inline void hist_body(int b, const int* __restrict__ dst,
                                 int* __restrict__ hist, int E, int chunk, int nbuck) {
    __shared__ int hl[256];
    int t = threadIdx.x;
    hl[t] = 0;
    __syncthreads();
    int start = b * chunk, end = min(E, start + chunk);
    for (int e = start + t; e < end; e += 256) atomicAdd(&hl[dst[e] >> 8], 1);
    __syncthreads();
    if (t < nbuck) hist[t * NBLK + b] = hl[t];
}

// W -> fragment-ordered bf16 hi/lo, column-permuted: physical slot (nt, lm)
// carries logical column n_l = lm*8 + nt (so epilogue stores are 16B packed).
__device__ inline void wfrag_body(int b, const float* __restrict__ W1,
                                  const float* __restrict__ W2,
                                  unsigned short* __restrict__ w1h,
                                  unsigned short* __restrict__ w1l,
                                  unsigned short* __restrict__ w2h,
                                  unsigned short* __restrict__ w2l) {
    const float* W = (b < 64) ? W1 : W2;
    unsigned short* whi = (b < 64) ? w1h : w2h;
    unsigned short* wlo = (b < 64) ? w1l : w2l;
    int idx = (b & 63) * 256 + threadIdx.x;     // 0..16383
    int k = idx >> 7;
    int n = idx & 127;
    int kt = k >> 5, q = (k >> 3) & 3, j = k & 7;
    int lm = n >> 3, nt = n & 7;
    int lane = q * 16 + lm;
    int o = ((kt * 8 + nt) * 64 + lane) * 8 + j;
    float x = W[idx];
    unsigned short hb = f2bf_rne(x);
    float hf = __uint_as_float(((unsigned)hb) << 16);
    unsigned short lb = f2bf_rne(x - hf);
    whi[o] = hb;
    wlo[o] = lb;
}

// Pass C: scatter edges into bucket-sorted order via LDS cursors (no global atomics).
__device__ inline void scatter_body(int b, const int* __restrict__ srcv,
                                    const int* __restrict__ dstv,
                                    const int* __restrict__ hscan,
                                    int2* __restrict__ sorted,
                                    int E, int chunk, int nbuck) {
    __shared__ int cur[256];
    int t = threadIdx.x;
    if (t < nbuck) cur[t] = hscan[t * NBLK + b];
    __syncthreads();
    int start = b * chunk, end = min(E, start + chunk);
    for (int e = start + t; e < end; e += 256) {
        int d = dstv[e];
        int pos = atomicAdd(&cur[d >> 8], 1);
        sorted[pos] = make_int2(srcv[e], d);
    }
}

// MFMA GEMM (fp32 A), 64-row tiles, split 3-MFMA: C ~= Ah*Wh + Al*Wh + Ah*Wl
// Output rows stored FP32 to mtmp; csr_kernel applies dinv and rounds to bf16
// (single rounding: bf16(dinv * fp32gemm), identical chain to proven numerics).
#define GBM 64
__device__ inline void gemm_f32_body(int b, const float* __restrict__ A,
                                     const unsigned short* __restrict__ whi,
                                     const unsigned short* __restrict__ wlo,
                                     float* __restrict__ C, int Nrows) {
    int tid = threadIdx.x;
    int w = tid >> 6, L = tid & 63;
    int lm = L & 15, lq = L >> 4;
    int row0 = b * GBM + w * 16;

    f32x4 acc[8];
#pragma unroll
    for (int nt = 0; nt < 8; ++nt) acc[nt] = (f32x4)(0.f);

#pragma unroll
    for (int kt = 0; kt < 4; ++kt) {
        int gr = row0 + lm;
        float4 v0 = make_float4(0.f, 0.f, 0.f, 0.f);
        float4 v1 = v0;
        if (gr < Nrows) {
            const float* p = &A[(size_t)gr * HDIM + kt * 32 + lq * 8];
            v0 = *(const float4*)p;
            v1 = *(const float4*)(p + 4);
        }
        float xv[8] = {v0.x, v0.y, v0.z, v0.w, v1.x, v1.y, v1.z, v1.w};
        bfrag ah, al;
#pragma unroll
        for (int j = 0; j < 8; ++j) {
            float x = xv[j];
            unsigned short hb = f2bf_rne(x);
            float hf = __uint_as_float(((unsigned)hb) << 16);
            unsigned short lb = f2bf_rne(x - hf);
            ah[j] = (short)hb;
            al[j] = (short)lb;
        }
#pragma unroll
        for (int nt = 0; nt < 8; ++nt) {
            int o = ((kt * 8 + nt) * 64 + L) * 8;
            bfrag wh = *(const bfrag*)&whi[o];
            bfrag wl = *(const bfrag*)&wlo[o];
            acc[nt] = __builtin_amdgcn_mfma_f32_16x16x32_bf16(ah, wh, acc[nt], 0, 0, 0);
            acc[nt] = __builtin_amdgcn_mfma_f32_16x16x32_bf16(al, wh, acc[nt], 0, 0, 0);
            acc[nt] = __builtin_amdgcn_mfma_f32_16x16x32_bf16(ah, wl, acc[nt], 0, 0, 0);
        }
    }

#pragma unroll
    for (int i = 0; i < 4; ++i) {
        int gr = row0 + lq * 4 + i;
        if (gr < Nrows) {
            float4 o0 = make_float4(acc[0][i], acc[1][i], acc[2][i], acc[3][i]);
            float4 o1 = make_float4(acc[4][i], acc[5][i], acc[6][i], acc[7][i]);
            *(float4*)&C[(size_t)gr * HDIM + lm * 8] = o0;
            *(float4*)&C[(size_t)gr * HDIM + lm * 8 + 4] = o1;
        }
    }
}

// ---------------- megakernel 1: hist || wfrag ----------------
__global__ __launch_bounds__(256) void mega1_kernel(const int* __restrict__ dst,
                                                    int* __restrict__ hist, int E,
                                                    int chunk, int nbuck,
                                                    const float* __restrict__ W1,
                                                    const float* __restrict__ W2,
                                                    unsigned short* __restrict__ w1h,
                                                    unsigned short* __restrict__ w1l,
                                                    unsigned short* __restrict__ w2h,
                                                    unsigned short* __restrict__ w2l) {
    int b = blockIdx.x;
    if (b < NBLK) hist_body(b, dst, hist, E, chunk, nbuck);
    else wfrag_body(b - NBLK, W1, W2, w1h, w1l, w2h, w2l);
}

// ---------------- megakernel 3: scatter || gemm_f32(layer1) ----------------
__global__ __launch_bounds__(256) void mega3_kernel(const int* __restrict__ srcv,
                                                    const int* __restrict__ dstv,
                                                    const int* __restrict__ hscan,
                                                    int2* __restrict__ sorted,
                                                    int E, int chunk, int nbuck,
                                                    const float* __restrict__ A,
                                                    const unsigned short* __restrict__ whi,
                                                    const unsigned short* __restrict__ wlo,
                                                    float* __restrict__ C, int Nrows) {
    int b = blockIdx.x;
    if (b < NBLK) scatter_body(b, srcv, dstv, hscan, sorted, E, chunk, nbuck);
    else gemm_f32_body(b - NBLK, A, whi, wlo, C, Nrows);
}

// ---------------- scan phase 1: per-block inclusive scan ----------------
__global__ __launch_bounds__(SCAN_B) void scan1_kernel(const int* __restrict__ in,
                                                       int* __restrict__ out,
                                                       int* __restrict__ sums, int n) {
    __shared__ int s[SCAN_B];
    int t = threadIdx.x;
    int idx = blockIdx.x * SCAN_B + t;
    int v = (idx < n) ? in[idx] : 0;
    s[t] = v;
    __syncthreads();
    for (int off = 1; off < SCAN_B; off <<= 1) {
        int x = (t >= off) ? s[t - off] : 0;
        __syncthreads();
        s[t] += x;
        __syncthreads();
    }
    if (idx < n) out[idx] = s[t];
    if (t == SCAN_B - 1) sums[blockIdx.x] = s[t];
}

// ---------------- scan phase 2+3 fused ----------------
__global__ __launch_bounds__(SCAN_B) void scan3_kernel(const int* __restrict__ in,
                                                       int* __restrict__ inout,
                                                       const int* __restrict__ sums,
                                                       int n) {
    __shared__ int s[SCAN_B];
    int t = threadIdx.x;
    int b = blockIdx.x;                 // gridDim.x <= 256 required
    s[t] = (t < b) ? sums[t] : 0;
    __syncthreads();
    for (int off = SCAN_B / 2; off > 0; off >>= 1) {
        if (t < off) s[t] += s[t + off];
        __syncthreads();
    }
    int base = s[0];
    int idx = b * SCAN_B + t;
    if (idx < n) inout[idx] = inout[idx] - in[idx] + base;
}

// ---------------- Pass D: per-bucket CSR build + m = bf16(dinv * mtmp) ----------------
__global__ __launch_bounds__(256) void csr_kernel(const int2* __restrict__ sorted,
                                                  const int* __restrict__ hscan,
                                                  int* __restrict__ rowstart,
                                                  float* __restrict__ dinv,
                                                  int* __restrict__ csr,
                                                  const float* __restrict__ mtmp,
                                                  unsigned short* __restrict__ m,
                                                  int N, int E, int nbuck) {
    __shared__ int cnt[256];
    __shared__ int s[256];
    __shared__ int cur[256];
    __shared__ float sdv[256];
    int b = blockIdx.x;
    int t = threadIdx.x;
    int start = hscan[b * NBLK];
    int end = (b + 1 < nbuck) ? hscan[(b + 1) * NBLK] : E;
    cnt[t] = 0;
    __syncthreads();
    for (int e = start + t; e < end; e += 256)
        atomicAdd(&cnt[sorted[e].y & 255], 1);
    __syncthreads();
    int v = cnt[t];
    s[t] = v;
    __syncthreads();
    for (int off = 1; off < 256; off <<= 1) {
        int x = (t >= off) ? s[t - off] : 0;
        __syncthreads();
        s[t] += x;
        __syncthreads();
    }
    int excl = s[t] - v;
    int node = b * 256 + t;
    float dv = rsqrtf((float)(v + 1));   // +1 self-loop
    sdv[t] = dv;
    if (node < N) {
        rowstart[node] = start + excl;
        dinv[node] = dv;
    }
    if (b == nbuck - 1 && t == 0) rowstart[N] = E;
    cur[t] = start + excl;
    __syncthreads();
    for (int e = start + t; e < end; e += 256) {
        int2 ed = sorted[e];
        int pos = atomicAdd(&cur[ed.y & 255], 1);
        csr[pos] = ed.x;
    }
    // ---- scale this block's 256 node rows: m = bf16(dinv * mtmp) ----
    const float4* mt4 = (const float4*)mtmp;
    uint2* m2p = (uint2*)m;
    for (int idx = t; idx < 256 * 32; idx += 256) {
        int r = idx >> 5, c = idx & 31;          // row-in-block, float4-in-row
        int nn = b * 256 + r;
        if (nn < N) {
            float4 v4 = mt4[(size_t)nn * 32 + c];
            float dd = sdv[r];
            unsigned short ev[4];
            ev[0] = f2bf_rne(dd * v4.x);
            ev[1] = f2bf_rne(dd * v4.y);
            ev[2] = f2bf_rne(dd * v4.z);
            ev[3] = f2bf_rne(dd * v4.w);
            m2p[(size_t)nn * 32 + c] = *(uint2*)ev;
        }
    }
}

// ---------------- quarter-wave gather, pure-add, vectorized index loads ----------------
// Rows pre-scaled by dinv[src] -> accumulation is pure adds, no per-edge weights.
#define QACC(UV)                                       \
    acc[0] += bf_lo((UV).x); acc[1] += bf_hi((UV).x);  \
    acc[2] += bf_lo((UV).y); acc[3] += bf_hi((UV).y);  \
    acc[4] += bf_lo((UV).z); acc[5] += bf_hi((UV).z);  \
    acc[6] += bf_lo((UV).w); acc[7] += bf_hi((UV).w);

__device__ inline void qgather(const uint4* __restrict__ m4,
                               const int* __restrict__ csr,
                               int p, int pend, int t, float* acc) {
    // scalar head until p is 4-aligned (so int4 index loads are 16B-aligned)
    while (p < pend && (p & 3)) {
        uint4 u0 = m4[(size_t)csr[p] * 16 + t];
        QACC(u0);
        ++p;
    }
    for (; p + 8 <= pend; p += 8) {
        int4 i0 = *(const int4*)&csr[p];
        int4 i1 = *(const int4*)&csr[p + 4];
        uint4 u0 = m4[(size_t)i0.x * 16 + t];
        uint4 u1 = m4[(size_t)i0.y * 16 + t];
        uint4 u2 = m4[(size_t)i0.z * 16 + t];
        uint4 u3 = m4[(size_t)i0.w * 16 + t];
        uint4 u4 = m4[(size_t)i1.x * 16 + t];
        uint4 u5 = m4[(size_t)i1.y * 16 + t];
        uint4 u6 = m4[(size_t)i1.z * 16 + t];
        uint4 u7 = m4[(size_t)i1.w * 16 + t];
        QACC(u0); QACC(u1); QACC(u2); QACC(u3);
        QACC(u4); QACC(u5); QACC(u6); QACC(u7);
    }
    if (p + 4 <= pend) {
        int4 i0 = *(const int4*)&csr[p];
        uint4 u0 = m4[(size_t)i0.x * 16 + t];
        uint4 u1 = m4[(size_t)i0.y * 16 + t];
        uint4 u2 = m4[(size_t)i0.z * 16 + t];
        uint4 u3 = m4[(size_t)i0.w * 16 + t];
        QACC(u0); QACC(u1); QACC(u2); QACC(u3);
        p += 4;
    }
    while (p < pend) {
        uint4 u0 = m4[(size_t)csr[p] * 16 + t];
        QACC(u0);
        ++p;
    }
}

// In-block degree sort: rank the block's 16 nodes by row length (desc) so each
// wave's 4 quarter-nodes have similar trip counts -> minimal exec-mask waste.
// Also stashes row starts/lengths in LDS. Returns permuted node-in-block.
__device__ inline int degree_perm(const int* __restrict__ rowstart,
                                  int* lens, int* rs, int* perm, int n) {
    if (threadIdx.x < 16) {
        int nn = blockIdx.x * 16 + threadIdx.x;
        int a = (nn < n) ? rowstart[nn] : 0;
        int bnd = (nn < n) ? rowstart[nn + 1] : 0;
        rs[threadIdx.x] = a;
        lens[threadIdx.x] = (nn < n) ? (bnd - a) : -1;
    }
    __syncthreads();
    if (threadIdx.x < 16) {
        int L = lens[threadIdx.x];
        int r = 0;
#pragma unroll
        for (int j = 0; j < 16; ++j) {
            int Lj = lens[j];
            r += (Lj > L || (Lj == L && j < (int)threadIdx.x)) ? 1 : 0;
        }
        perm[r] = threadIdx.x;
    }
    __syncthreads();
    return perm[threadIdx.x >> 4];
}

// ---------------- fused agg(layer1) + gemm(layer2): m2 = dinv*bf16(relu(agg)+b1)@W2 ----------------
__global__ __launch_bounds__(256) void agg_gemm_kernel(
        const uint4* __restrict__ m4,
        const int* __restrict__ rowstart,
        const int* __restrict__ csr,
        const float* __restrict__ dinv,
        const float* __restrict__ bias,
        const unsigned short* __restrict__ whi,   // W2 frags
        const unsigned short* __restrict__ wlo,
        uint4* __restrict__ out_m, int n) {
    __shared__ unsigned short hbuf[16][HDIM + 8];   // bf16 h tile (+16B pad)
    __shared__ float cbuf[16][HDIM + 4];            // fp32 C tile (+16B pad)
    __shared__ int lens[16];
    __shared__ int rs[16];
    __shared__ int perm[16];
    int t = threadIdx.x & 15;

    int pnl = degree_perm(rowstart, lens, rs, perm, n);
    int node = blockIdx.x * 16 + pnl;

    // ---- agg phase (processes node `pnl`, writes hbuf[pnl]) ----
    unsigned short hv[8] = {0, 0, 0, 0, 0, 0, 0, 0};
    if (node < n) {
        float dd = dinv[node];
        float acc[8];
        uint4 u = m4[(size_t)node * 16 + t];        // self term: row already dinv-scaled
        acc[0] = bf_lo(u.x); acc[1] = bf_hi(u.x);
        acc[2] = bf_lo(u.y); acc[3] = bf_hi(u.y);
        acc[4] = bf_lo(u.z); acc[5] = bf_hi(u.z);
        acc[6] = bf_lo(u.w); acc[7] = bf_hi(u.w);
        int p0 = rs[pnl];
        qgather(m4, csr, p0, p0 + lens[pnl], t, acc);
        float4 b0 = *(const float4*)&bias[t * 8];
        float4 b1 = *(const float4*)&bias[t * 8 + 4];
        float bb[8] = {b0.x, b0.y, b0.z, b0.w, b1.x, b1.y, b1.z, b1.w};
#pragma unroll
        for (int j = 0; j < 8; ++j)
            hv[j] = f2bf_rne(fmaxf(fmaf(dd, acc[j], bb[j]), 0.f));
    }
    *(uint4*)&hbuf[pnl][t * 8] = *(uint4*)hv;
    __syncthreads();

    // ---- gemm phase: each wave does 2 column tiles, all 4 kt ----
    int w = threadIdx.x >> 6, L = threadIdx.x & 63;
    int lm = L & 15, lq = L >> 4;
    f32x4 acc2[2];
    acc2[0] = (f32x4)(0.f);
    acc2[1] = (f32x4)(0.f);
#pragma unroll
    for (int kt = 0; kt < 4; ++kt) {
        bfrag a = *(const bfrag*)&hbuf[lm][kt * 32 + lq * 8];
#pragma unroll
        for (int q2 = 0; q2 < 2; ++q2) {
            int nt = w * 2 + q2;
            int o = ((kt * 8 + nt) * 64 + L) * 8;
            bfrag wh = *(const bfrag*)&whi[o];
            bfrag wl = *(const bfrag*)&wlo[o];
            acc2[q2] = __builtin_amdgcn_mfma_f32_16x16x32_bf16(a, wh, acc2[q2], 0, 0, 0);
            acc2[q2] = __builtin_amdgcn_mfma_f32_16x16x32_bf16(a, wl, acc2[q2], 0, 0, 0);
        }
    }
    // C/D layout: col(in tile)=lane&15, row=(lane>>4)*4+i; logical col = lm*8+nt
#pragma unroll
    for (int q2 = 0; q2 < 2; ++q2) {
        int nt = w * 2 + q2;
#pragma unroll
        for (int i = 0; i < 4; ++i) cbuf[lq * 4 + i][lm * 8 + nt] = acc2[q2][i];
    }
    __syncthreads();

    // ---- repack + pre-scale by dinv + round + store (original node order) ----
    int nl = threadIdx.x >> 4;
    int node_e = blockIdx.x * 16 + nl;
    if (node_e < n) {
        float dde = dinv[node_e];
        float4 r0 = *(const float4*)&cbuf[nl][t * 8];
        float4 r1 = *(const float4*)&cbuf[nl][t * 8 + 4];
        unsigned short ev[8];
        ev[0] = f2bf_rne(dde * r0.x); ev[1] = f2bf_rne(dde * r0.y);
        ev[2] = f2bf_rne(dde * r0.z); ev[3] = f2bf_rne(dde * r0.w);
        ev[4] = f2bf_rne(dde * r1.x); ev[5] = f2bf_rne(dde * r1.y);
        ev[6] = f2bf_rne(dde * r1.z); ev[7] = f2bf_rne(dde * r1.w);
        out_m[(size_t)node_e * 16 + t] = *(uint4*)ev;
    }
}

// ---------------- agg layer 2 fused with global max pool ----------------
__global__ __launch_bounds__(256) void agg_pool_kernel(const uint4* __restrict__ m4,
                                                       const int* __restrict__ rowstart,
                                                       const int* __restrict__ csr,
                                                       const float* __restrict__ dinv,
                                                       const float* __restrict__ bias,
                                                       const int* __restrict__ batch,
                                                       unsigned int* __restrict__ g, int n) {
    __shared__ float smx[16][HDIM];
    __shared__ int sgid[16];
    __shared__ int lens[16];
    __shared__ int rs[16];
    __shared__ int perm[16];
    int t = threadIdx.x & 15;

    int pnl = degree_perm(rowstart, lens, rs, perm, n);
    int node = blockIdx.x * 16 + pnl;
    bool valid = node < n;
    if (valid) {
        float dd = dinv[node];
        float acc[8];
        uint4 u = m4[(size_t)node * 16 + t];
        acc[0] = bf_lo(u.x); acc[1] = bf_hi(u.x);
        acc[2] = bf_lo(u.y); acc[3] = bf_hi(u.y);
        acc[4] = bf_lo(u.z); acc[5] = bf_hi(u.z);
        acc[6] = bf_lo(u.w); acc[7] = bf_hi(u.w);
        int p0 = rs[pnl];
        qgather(m4, csr, p0, p0 + lens[pnl], t, acc);
        float4 b0 = *(const float4*)&bias[t * 8];
        float4 b1 = *(const float4*)&bias[t * 8 + 4];
        float4 r0, r1;
        r0.x = fmaxf(fmaf(dd, acc[0], b0.x), 0.f);
        r0.y = fmaxf(fmaf(dd, acc[1], b0.y), 0.f);
        r0.z = fmaxf(fmaf(dd, acc[2], b0.z), 0.f);
        r0.w = fmaxf(fmaf(dd, acc[3], b0.w), 0.f);
        r1.x = fmaxf(fmaf(dd, acc[4], b1.x), 0.f);
        r1.y = fmaxf(fmaf(dd, acc[5], b1.y), 0.f);
        r1.z = fmaxf(fmaf(dd, acc[6], b1.z), 0.f);
        r1.w = fmaxf(fmaf(dd, acc[7], b1.w), 0.f);
        *(float4*)&smx[pnl][t * 8] = r0;
        *(float4*)&smx[pnl][t * 8 + 4] = r1;
    }
    if (t == 0) sgid[pnl] = valid ? batch[node] : -1;
    __syncthreads();
    // smx/sgid are indexed by original node order -> batch runs stay contiguous.
    if (threadIdx.x < HDIM) {
        int c = threadIdx.x;
        int curg = -1;
        float run = 0.f;
#pragma unroll
        for (int r = 0; r < 16; ++r) {
            int gg = sgid[r];
            if (gg < 0) continue;
            if (gg != curg) {
                if (curg >= 0) atomicMax(&g[curg * HDIM + c], __float_as_uint(run));
                curg = gg;
                run = smx[r][c];
            } else {
                run = fmaxf(run, smx[r][c]);
            }
        }
        if (curg >= 0) atomicMax(&g[curg * HDIM + c], __float_as_uint(run));
    }
}

// ---------------- MLP head + log_softmax ----------------
__global__ __launch_bounds__(128) void mlp_kernel(const unsigned int* __restrict__ gbits,
                                                  const float* __restrict__ W3,
                                                  const float* __restrict__ b3,
                                                  const float* __restrict__ W4,
                                                  const float* __restrict__ b4,
                                                  float* __restrict__ out) {
    __shared__ float gs[HDIM];
    __shared__ float r0[HDIM];
    __shared__ float r1[HDIM];
    int j = threadIdx.x;
    int b = blockIdx.x;
    gs[j] = __uint_as_float(gbits[b * HDIM + j]);
    __syncthreads();
    float acc = b3[j];
#pragma unroll 8
    for (int k = 0; k < HDIM; ++k) acc = fmaf(gs[k], W3[k * HDIM + j], acc);
    float z = fmaxf(acc, 0.f);
    r0[j] = z * W4[j * 2 + 0];
    r1[j] = z * W4[j * 2 + 1];
    __syncthreads();
    for (int off = 64; off > 0; off >>= 1) {
        if (j < off) {
            r0[j] += r0[j + off];
            r1[j] += r1[j + off];
        }
        __syncthreads();
    }
    if (j == 0) {
        float l0 = r0[0] + b4[0];
        float l1 = r1[0] + b4[1];
        float mx = fmaxf(l0, l1);
        float lse = mx + logf(expf(l0 - mx) + expf(l1 - mx));
        out[b * 2 + 0] = l0 - lse;
        out[b * 2 + 1] = l1 - lse;
    }
}

extern "C" void kernel_launch(void* const* d_in, const int* in_sizes, int n_in,
                              void* d_out, int out_size, void* d_ws, size_t ws_size,
                              hipStream_t stream) {
    const float* x  = (const float*)d_in[0];
    const float* W1 = (const float*)d_in[1];
    const float* b1 = (const float*)d_in[2];
    const float* W2 = (const float*)d_in[3];
    const float* b2 = (const float*)d_in[4];
    const float* W3 = (const float*)d_in[5];
    const float* b3 = (const float*)d_in[6];
    const float* W4 = (const float*)d_in[7];
    const float* b4 = (const float*)d_in[8];
    const int* ei    = (const int*)d_in[9];
    const int* batch = (const int*)d_in[10];

    const int N = in_sizes[0] / HDIM;   // 50000
    const int E = in_sizes[9] / 2;      // 640000
    const int G = out_size / 2;         // 64
    const int* src = ei;
    const int* dst = ei + E;

    const int nbuck = (N + 255) >> 8;        // 196 (must be <= 256)
    const int nscan = nbuck * NBLK;          // 50176
    const int chunk = (E + NBLK - 1) / NBLK; // 2500

    // ---- workspace layout (16B-aligned blocks) ----
    const int Nr = ((N + 63) / 64) * 64;
    char* wsb = (char*)d_ws;
    size_t o = 0;
    unsigned int* g = (unsigned int*)(wsb + o); o += (size_t)G * HDIM * 4;
    size_t zero_bytes = o;                 // only g needs zeroing
    int* hist = (int*)(wsb + o);           o += (size_t)nscan * 4;
    int* hscan = (int*)(wsb + o);          o += (size_t)nscan * 4;
    int* sums = (int*)(wsb + o);           o += 256 * 4;
    int* rowstart = (int*)(wsb + o);       o += (size_t)(Nr + 64) * 4;
    float* dinv = (float*)(wsb + o);       o += (size_t)Nr * 4;
    int2* sorted = (int2*)(wsb + o);       o += (size_t)E * 8;
    int* csr = (int*)(wsb + o);            o += (size_t)E * 4;
    unsigned short* wf1h = (unsigned short*)(wsb + o); o += (size_t)HDIM * HDIM * 2;
    unsigned short* wf1l = (unsigned short*)(wsb + o); o += (size_t)HDIM * HDIM * 2;
    unsigned short* wf2h = (unsigned short*)(wsb + o); o += (size_t)HDIM * HDIM * 2;
    unsigned short* wf2l = (unsigned short*)(wsb + o); o += (size_t)HDIM * HDIM * 2;
    unsigned short* m = (unsigned short*)(wsb + o);    o += (size_t)Nr * HDIM * 2;
    unsigned short* m2 = (unsigned short*)(wsb + o);   o += (size_t)Nr * HDIM * 2;
    float* mtmp = (float*)(wsb + o);       o += (size_t)Nr * HDIM * 4;
    (void)ws_size; (void)n_in;

    (void)hipMemsetAsync(d_ws, 0, zero_bytes, stream);

    int sblocks = (nscan + SCAN_B - 1) / SCAN_B;   // 196 (<= 256 required)
    int gemm_blocks = (N + GBM - 1) / GBM;         // 782
    int agg_blocks = (N + 15) / 16;                // 3125

    // K1: hist || wfrag  (independent)
    mega1_kernel<<<NBLK + 128, 256, 0, stream>>>(dst, hist, E, chunk, nbuck,
                                                 W1, W2, wf1h, wf1l, wf2h, wf2l);
    // K2: scan of hist matrix (bucket-major) -> hscan exclusive (2 dispatches)
    scan1_kernel<<<sblocks, SCAN_B, 0, stream>>>(hist, hscan, sums, nscan);
    scan3_kernel<<<sblocks, SCAN_B, 0, stream>>>(hist, hscan, sums, nscan);
    // K3: scatter (bucket sort) || gemm layer 1 -> mtmp (fp32, unscaled)
    mega3_kernel<<<NBLK + gemm_blocks, 256, 0, stream>>>(src, dst, hscan, sorted,
                                                         E, chunk, nbuck,
                                                         x, wf1h, wf1l, mtmp, N);
    // K4: per-bucket CSR build (rowstart, dinv, csr) + m = bf16(dinv*mtmp)
    csr_kernel<<<nbuck, 256, 0, stream>>>(sorted, hscan, rowstart, dinv, csr,
                                          mtmp, m, N, E, nbuck);
    // K5: fused agg(layer1) + gemm(layer2) -> m2 (dinv-pre-scaled)
    agg_gemm_kernel<<<agg_blocks, 256, 0, stream>>>((const uint4*)m, rowstart, csr,
                                                    dinv, b1, wf2h, wf2l,
                                                    (uint4*)m2, N);
    // K6: agg layer 2 + global max pool
    agg_pool_kernel<<<agg_blocks, 256, 0, stream>>>((const uint4*)m2, rowstart, csr,
                                                    dinv, b2, batch, g, N);
    // K7: MLP head + log_softmax
    mlp_kernel<<<G, 128, 0, stream>>>(g, W3, b3, W4, b4, (float*)d_out);
}

// Round 5
// 210.184 us; speedup vs baseline: 1.0297x; 1.0297x over previous
//
#include <hip/hip_runtime.h>
#include <hip/hip_bf16.h>
#include <math.h>

// ---------------- constants ----------------
#define HDIM 128
#define SCAN_B 256
#define NBLK 256          // edge blocks for hist/scatter passes

typedef short bfrag __attribute__((ext_vector_type(8)));   // 8 bf16 (4 VGPRs)
typedef float f32x4 __attribute__((ext_vector_type(4)));   // 4 fp32 acc

__device__ inline unsigned short f2bf_rne(float x) {
    unsigned u = __float_as_uint(x);
    u = (u + 0x7fffu + ((u >> 16) & 1u)) >> 16;
    return (unsigned short)u;
}
__device__ inline float bf_lo(unsigned u) { return __uint_as_float(u << 16); }
__device__ inline float bf_hi(unsigned u) { return __uint_as_float(u & 0xffff0000u); }

// ---------------- device bodies ----------------

// Pass A: per-block LDS coarse histogram (dst>>8); no global atomics.
__device__ inline void hist_body(int b, const int* __restrict__ dst,
                                 int* __restrict__ hist, int E, int chunk, int nbuck) {
    __shared__ int hl[256];
    int t = threadIdx.x;
    hl[t] = 0;
    __syncthreads();
    int start = b * chunk, end = min(E, start + chunk);
    for (int e = start + t; e < end; e += 256) atomicAdd(&hl[dst[e] >> 8], 1);
    __syncthreads();
    if (t < nbuck) hist[t * NBLK + b] = hl[t];
}

// W -> fragment-ordered bf16 hi/lo, column-permuted: physical slot (nt, lm)
// carries logical column n_l = lm*8 + nt (so epilogue stores are 16B packed).
__device__ inline void wfrag_body(int b, const float* __restrict__ W1,
                                  const float* __restrict__ W2,
                                  unsigned short* __restrict__ w1h,
                                  unsigned short* __restrict__ w1l,
                                  unsigned short* __restrict__ w2h,
                                  unsigned short* __restrict__ w2l) {
    const float* W = (b < 64) ? W1 : W2;
    unsigned short* whi = (b < 64) ? w1h : w2h;
    unsigned short* wlo = (b < 64) ? w1l : w2l;
    int idx = (b & 63) * 256 + threadIdx.x;     // 0..16383
    int k = idx >> 7;
    int n = idx & 127;
    int kt = k >> 5, q = (k >> 3) & 3, j = k & 7;
    int lm = n >> 3, nt = n & 7;
    int lane = q * 16 + lm;
    int o = ((kt * 8 + nt) * 64 + lane) * 8 + j;
    float x = W[idx];
    unsigned short hb = f2bf_rne(x);
    float hf = __uint_as_float(((unsigned)hb) << 16);
    unsigned short lb = f2bf_rne(x - hf);
    whi[o] = hb;
    wlo[o] = lb;
}

// Pass C: scatter edges into bucket-sorted order via LDS cursors (no global atomics).
__device__ inline void scatter_body(int b, const int* __restrict__ srcv,
                                    const int* __restrict__ dstv,
                                    const int* __restrict__ hscan,
                                    int2* __restrict__ sorted,
                                    int E, int chunk, int nbuck) {
    __shared__ int cur[256];
    int t = threadIdx.x;
    if (t < nbuck) cur[t] = hscan[t * NBLK + b];
    __syncthreads();
    int start = b * chunk, end = min(E, start + chunk);
    for (int e = start + t; e < end; e += 256) {
        int d = dstv[e];
        int pos = atomicAdd(&cur[d >> 8], 1);
        sorted[pos] = make_int2(srcv[e], d);
    }
}

// MFMA GEMM (fp32 A), 64-row tiles, split 3-MFMA: C ~= Ah*Wh + Al*Wh + Ah*Wl
#define GBM 64
__device__ inline void gemm_f32_body(int b, const float* __restrict__ A,
                                     const unsigned short* __restrict__ whi,
                                     const unsigned short* __restrict__ wlo,
                                     unsigned short* __restrict__ C, int Nrows) {
    int tid = threadIdx.x;
    int w = tid >> 6, L = tid & 63;
    int lm = L & 15, lq = L >> 4;
    int row0 = b * GBM + w * 16;

    f32x4 acc[8];
#pragma unroll
    for (int nt = 0; nt < 8; ++nt) acc[nt] = (f32x4)(0.f);

#pragma unroll
    for (int kt = 0; kt < 4; ++kt) {
        int gr = row0 + lm;
        float4 v0 = make_float4(0.f, 0.f, 0.f, 0.f);
        float4 v1 = v0;
        if (gr < Nrows) {
            const float* p = &A[(size_t)gr * HDIM + kt * 32 + lq * 8];
            v0 = *(const float4*)p;
            v1 = *(const float4*)(p + 4);
        }
        float xv[8] = {v0.x, v0.y, v0.z, v0.w, v1.x, v1.y, v1.z, v1.w};
        bfrag ah, al;
#pragma unroll
        for (int j = 0; j < 8; ++j) {
            float x = xv[j];
            unsigned short hb = f2bf_rne(x);
            float hf = __uint_as_float(((unsigned)hb) << 16);
            unsigned short lb = f2bf_rne(x - hf);
            ah[j] = (short)hb;
            al[j] = (short)lb;
        }
#pragma unroll
        for (int nt = 0; nt < 8; ++nt) {
            int o = ((kt * 8 + nt) * 64 + L) * 8;
            bfrag wh = *(const bfrag*)&whi[o];
            bfrag wl = *(const bfrag*)&wlo[o];
            acc[nt] = __builtin_amdgcn_mfma_f32_16x16x32_bf16(ah, wh, acc[nt], 0, 0, 0);
            acc[nt] = __builtin_amdgcn_mfma_f32_16x16x32_bf16(al, wh, acc[nt], 0, 0, 0);
            acc[nt] = __builtin_amdgcn_mfma_f32_16x16x32_bf16(ah, wl, acc[nt], 0, 0, 0);
        }
    }

#pragma unroll
    for (int i = 0; i < 4; ++i) {
        int gr = row0 + lq * 4 + i;
        if (gr < Nrows) {
            bfrag e;
#pragma unroll
            for (int nt = 0; nt < 8; ++nt) e[nt] = (short)f2bf_rne(acc[nt][i]);
            *(bfrag*)&C[(size_t)gr * HDIM + lm * 8] = e;
        }
    }
}

// ---------------- megakernel 1: hist || wfrag ----------------
__global__ __launch_bounds__(256) void mega1_kernel(const int* __restrict__ dst,
                                                    int* __restrict__ hist, int E,
                                                    int chunk, int nbuck,
                                                    const float* __restrict__ W1,
                                                    const float* __restrict__ W2,
                                                    unsigned short* __restrict__ w1h,
                                                    unsigned short* __restrict__ w1l,
                                                    unsigned short* __restrict__ w2h,
                                                    unsigned short* __restrict__ w2l) {
    int b = blockIdx.x;
    if (b < NBLK) hist_body(b, dst, hist, E, chunk, nbuck);
    else wfrag_body(b - NBLK, W1, W2, w1h, w1l, w2h, w2l);
}

// ---------------- megakernel 3: scatter || gemm_f32(layer1) ----------------
__global__ __launch_bounds__(256) void mega3_kernel(const int* __restrict__ srcv,
                                                    const int* __restrict__ dstv,
                                                    const int* __restrict__ hscan,
                                                    int2* __restrict__ sorted,
                                                    int E, int chunk, int nbuck,
                                                    const float* __restrict__ A,
                                                    const unsigned short* __restrict__ whi,
                                                    const unsigned short* __restrict__ wlo,
                                                    unsigned short* __restrict__ C, int Nrows) {
    int b = blockIdx.x;
    if (b < NBLK) scatter_body(b, srcv, dstv, hscan, sorted, E, chunk, nbuck);
    else gemm_f32_body(b - NBLK, A, whi, wlo, C, Nrows);
}

// ---------------- scan phase 1: per-block inclusive scan ----------------
__global__ __launch_bounds__(SCAN_B) void scan1_kernel(const int* __restrict__ in,
                                                       int* __restrict__ out,
                                                       int* __restrict__ sums, int n) {
    __shared__ int s[SCAN_B];
    int t = threadIdx.x;
    int idx = blockIdx.x * SCAN_B + t;
    int v = (idx < n) ? in[idx] : 0;
    s[t] = v;
    __syncthreads();
    for (int off = 1; off < SCAN_B; off <<= 1) {
        int x = (t >= off) ? s[t - off] : 0;
        __syncthreads();
        s[t] += x;
        __syncthreads();
    }
    if (idx < n) out[idx] = s[t];
    if (t == SCAN_B - 1) sums[blockIdx.x] = s[t];
}

// ---------------- scan phase 2+3 fused ----------------
__global__ __launch_bounds__(SCAN_B) void scan3_kernel(const int* __restrict__ in,
                                                       int* __restrict__ inout,
                                                       const int* __restrict__ sums,
                                                       int n) {
    __shared__ int s[SCAN_B];
    int t = threadIdx.x;
    int b = blockIdx.x;                 // gridDim.x <= 256 required
    s[t] = (t < b) ? sums[t] : 0;
    __syncthreads();
    for (int off = SCAN_B / 2; off > 0; off >>= 1) {
        if (t < off) s[t] += s[t + off];
        __syncthreads();
    }
    int base = s[0];
    int idx = b * SCAN_B + t;
    if (idx < n) inout[idx] = inout[idx] - in[idx] + base;
}

// ---------------- Pass D: per-bucket CSR build (LDS atomics only) ----------------
__global__ __launch_bounds__(256) void csr_kernel(const int2* __restrict__ sorted,
                                                  const int* __restrict__ hscan,
                                                  int* __restrict__ rowstart,
                                                  float* __restrict__ dinv,
                                                  int* __restrict__ csr,
                                                  int N, int E, int nbuck) {
    __shared__ int cnt[256];
    __shared__ int s[256];
    __shared__ int cur[256];
    int b = blockIdx.x;
    int t = threadIdx.x;
    int start = hscan[b * NBLK];
    int end = (b + 1 < nbuck) ? hscan[(b + 1) * NBLK] : E;
    cnt[t] = 0;
    __syncthreads();
    for (int e = start + t; e < end; e += 256)
        atomicAdd(&cnt[sorted[e].y & 255], 1);
    __syncthreads();
    int v = cnt[t];
    s[t] = v;
    __syncthreads();
    for (int off = 1; off < 256; off <<= 1) {
        int x = (t >= off) ? s[t - off] : 0;
        __syncthreads();
        s[t] += x;
        __syncthreads();
    }
    int excl = s[t] - v;
    int node = b * 256 + t;
    if (node < N) {
        rowstart[node] = start + excl;
        dinv[node] = rsqrtf((float)(v + 1));   // +1 self-loop
    }
    if (b == nbuck - 1 && t == 0) rowstart[N] = E;
    cur[t] = start + excl;
    __syncthreads();
    for (int e = start + t; e < end; e += 256) {
        int2 ed = sorted[e];
        int pos = atomicAdd(&cur[ed.y & 255], 1);
        csr[pos] = ed.x;
    }
}

// ---------------- gather primitives ----------------
// WEIGHTED: acc += dinv[s] * m[s]  (layer-1 rows unscaled)
// !WEIGHTED: acc += m[s]           (layer-2 rows pre-scaled by dinv[src])
template <bool W>
__device__ inline void qacc1(float* acc, uint4 uv, float wt) {
    if (W) {
        acc[0] = fmaf(wt, bf_lo(uv.x), acc[0]);
        acc[1] = fmaf(wt, bf_hi(uv.x), acc[1]);
        acc[2] = fmaf(wt, bf_lo(uv.y), acc[2]);
        acc[3] = fmaf(wt, bf_hi(uv.y), acc[3]);
        acc[4] = fmaf(wt, bf_lo(uv.z), acc[4]);
        acc[5] = fmaf(wt, bf_hi(uv.z), acc[5]);
        acc[6] = fmaf(wt, bf_lo(uv.w), acc[6]);
        acc[7] = fmaf(wt, bf_hi(uv.w), acc[7]);
    } else {
        acc[0] += bf_lo(uv.x); acc[1] += bf_hi(uv.x);
        acc[2] += bf_lo(uv.y); acc[3] += bf_hi(uv.y);
        acc[4] += bf_lo(uv.z); acc[5] += bf_hi(uv.z);
        acc[6] += bf_lo(uv.w); acc[7] += bf_hi(uv.w);
    }
}

// single-stream 8-deep drain
template <bool W>
__device__ inline void qgather(const uint4* __restrict__ m4,
                               const int* __restrict__ csr,
                               const float* __restrict__ dinv,
                               int p, int pend, int t, float* acc) {
    for (; p + 8 <= pend; p += 8) {
        int s0 = csr[p], s1 = csr[p + 1], s2 = csr[p + 2], s3 = csr[p + 3];
        int s4 = csr[p + 4], s5 = csr[p + 5], s6 = csr[p + 6], s7 = csr[p + 7];
        float w0 = 0.f, w1 = 0.f, w2 = 0.f, w3 = 0.f;
        float w4 = 0.f, w5 = 0.f, w6 = 0.f, w7 = 0.f;
        if (W) {
            w0 = dinv[s0]; w1 = dinv[s1]; w2 = dinv[s2]; w3 = dinv[s3];
            w4 = dinv[s4]; w5 = dinv[s5]; w6 = dinv[s6]; w7 = dinv[s7];
        }
        uint4 u0 = m4[(size_t)s0 * 16 + t];
        uint4 u1 = m4[(size_t)s1 * 16 + t];
        uint4 u2 = m4[(size_t)s2 * 16 + t];
        uint4 u3 = m4[(size_t)s3 * 16 + t];
        uint4 u4 = m4[(size_t)s4 * 16 + t];
        uint4 u5 = m4[(size_t)s5 * 16 + t];
        uint4 u6 = m4[(size_t)s6 * 16 + t];
        uint4 u7 = m4[(size_t)s7 * 16 + t];
        qacc1<W>(acc, u0, w0); qacc1<W>(acc, u1, w1);
        qacc1<W>(acc, u2, w2); qacc1<W>(acc, u3, w3);
        qacc1<W>(acc, u4, w4); qacc1<W>(acc, u5, w5);
        qacc1<W>(acc, u6, w6); qacc1<W>(acc, u7, w7);
    }
    if (p + 4 <= pend) {
        int s0 = csr[p], s1 = csr[p + 1], s2 = csr[p + 2], s3 = csr[p + 3];
        float w0 = 0.f, w1 = 0.f, w2 = 0.f, w3 = 0.f;
        if (W) { w0 = dinv[s0]; w1 = dinv[s1]; w2 = dinv[s2]; w3 = dinv[s3]; }
        uint4 u0 = m4[(size_t)s0 * 16 + t];
        uint4 u1 = m4[(size_t)s1 * 16 + t];
        uint4 u2 = m4[(size_t)s2 * 16 + t];
        uint4 u3 = m4[(size_t)s3 * 16 + t];
        qacc1<W>(acc, u0, w0); qacc1<W>(acc, u1, w1);
        qacc1<W>(acc, u2, w2); qacc1<W>(acc, u3, w3);
        p += 4;
    }
    if (p + 2 <= pend) {
        int s0 = csr[p], s1 = csr[p + 1];
        float w0 = 0.f, w1 = 0.f;
        if (W) { w0 = dinv[s0]; w1 = dinv[s1]; }
        uint4 u0 = m4[(size_t)s0 * 16 + t];
        uint4 u1 = m4[(size_t)s1 * 16 + t];
        qacc1<W>(acc, u0, w0); qacc1<W>(acc, u1, w1);
        p += 2;
    }
    if (p < pend) {
        int s0 = csr[p];
        float w0 = W ? dinv[s0] : 0.f;
        uint4 u0 = m4[(size_t)s0 * 16 + t];
        qacc1<W>(acc, u0, w0);
    }
}

// dual-stream interleaved gather: two independent 4-edge batches in flight
// (doubles memory-level parallelism per quarter; streams are degree-matched).
template <bool W>
__device__ inline void dual_gather(const uint4* __restrict__ m4,
                                   const int* __restrict__ csr,
                                   const float* __restrict__ dinv,
                                   int pA, int pAe, int pB, int pBe, int t,
                                   float* aA, float* aB) {
    while (pA + 4 <= pAe && pB + 4 <= pBe) {
        int a0 = csr[pA], a1 = csr[pA + 1], a2 = csr[pA + 2], a3 = csr[pA + 3];
        int b0 = csr[pB], b1 = csr[pB + 1], b2 = csr[pB + 2], b3 = csr[pB + 3];
        float wa0 = 0.f, wa1 = 0.f, wa2 = 0.f, wa3 = 0.f;
        float wb0 = 0.f, wb1 = 0.f, wb2 = 0.f, wb3 = 0.f;
        if (W) {
            wa0 = dinv[a0]; wa1 = dinv[a1]; wa2 = dinv[a2]; wa3 = dinv[a3];
            wb0 = dinv[b0]; wb1 = dinv[b1]; wb2 = dinv[b2]; wb3 = dinv[b3];
        }
        uint4 uA0 = m4[(size_t)a0 * 16 + t];
        uint4 uA1 = m4[(size_t)a1 * 16 + t];
        uint4 uA2 = m4[(size_t)a2 * 16 + t];
        uint4 uA3 = m4[(size_t)a3 * 16 + t];
        uint4 uB0 = m4[(size_t)b0 * 16 + t];
        uint4 uB1 = m4[(size_t)b1 * 16 + t];
        uint4 uB2 = m4[(size_t)b2 * 16 + t];
        uint4 uB3 = m4[(size_t)b3 * 16 + t];
        qacc1<W>(aA, uA0, wa0); qacc1<W>(aB, uB0, wb0);
        qacc1<W>(aA, uA1, wa1); qacc1<W>(aB, uB1, wb1);
        qacc1<W>(aA, uA2, wa2); qacc1<W>(aB, uB2, wb2);
        qacc1<W>(aA, uA3, wa3); qacc1<W>(aB, uB3, wb3);
        pA += 4; pB += 4;
    }
    qgather<W>(m4, csr, dinv, pA, pAe, t, aA);
    qgather<W>(m4, csr, dinv, pB, pBe, t, aB);
}

// In-block degree sort over 32 nodes: rank by row length desc; quarter q gets
// ranks {2q, 2q+1} -> its two interleaved streams are degree-matched, and waves
// (8 consecutive ranks) are internally balanced.
__device__ inline void degree_perm32(const int* __restrict__ rowstart,
                                     int* lens, int* rs, int* perm, int n) {
    if (threadIdx.x < 32) {
        int nn = blockIdx.x * 32 + threadIdx.x;
        int a = (nn < n) ? rowstart[nn] : 0;
        int b2 = (nn < n) ? rowstart[nn + 1] : 0;
        rs[threadIdx.x] = a;
        lens[threadIdx.x] = (nn < n) ? (b2 - a) : -1;
    }
    __syncthreads();
    if (threadIdx.x < 32) {
        int L = lens[threadIdx.x];
        int r = 0;
#pragma unroll
        for (int j = 0; j < 32; ++j) {
            int Lj = lens[j];
            r += (Lj > L || (Lj == L && j < (int)threadIdx.x)) ? 1 : 0;
        }
        perm[r] = threadIdx.x;
    }
    __syncthreads();
}

// ---------------- fused agg(layer1) + gemm(layer2): m2 = dinv*bf16(relu(agg)+b1)@W2 ----------------
// Per block: 32 nodes, dual-node quarters. Weighted gather (m unscaled), round h
// to bf16 in LDS, in-block 32x128 @ 128x128 MFMA (2 row tiles), write m2 rows
// packed bf16 PRE-SCALED by dinv[node].
__global__ __launch_bounds__(256) void agg_gemm_kernel(
        const uint4* __restrict__ m4,
        const int* __restrict__ rowstart,
        const int* __restrict__ csr,
        const float* __restrict__ dinv,
        const float* __restrict__ bias,
        const unsigned short* __restrict__ whi,   // W2 frags
        const unsigned short* __restrict__ wlo,
        uint4* __restrict__ out_m, int n) {
    __shared__ unsigned short hbuf[32][HDIM + 8];   // bf16 h tile (+16B pad)
    __shared__ float cbuf[32][HDIM + 4];            // fp32 C tile (+16B pad)
    __shared__ int lens[32];
    __shared__ int rs[32];
    __shared__ int perm[32];
    int t = threadIdx.x & 15;
    int qid = threadIdx.x >> 4;                     // 0..15

    degree_perm32(rowstart, lens, rs, perm, n);
    int pnlA = perm[2 * qid], pnlB = perm[2 * qid + 1];
    int nodeA = blockIdx.x * 32 + pnlA;
    int nodeB = blockIdx.x * 32 + pnlB;
    bool vA = nodeA < n, vB = nodeB < n;

    // ---- agg phase: two interleaved streams per quarter ----
    float aA[8] = {0, 0, 0, 0, 0, 0, 0, 0};
    float aB[8] = {0, 0, 0, 0, 0, 0, 0, 0};
    float ddA = 0.f, ddB = 0.f;
    if (vA) {
        ddA = dinv[nodeA];
        uint4 u = m4[(size_t)nodeA * 16 + t];
        aA[0] = ddA * bf_lo(u.x); aA[1] = ddA * bf_hi(u.x);
        aA[2] = ddA * bf_lo(u.y); aA[3] = ddA * bf_hi(u.y);
        aA[4] = ddA * bf_lo(u.z); aA[5] = ddA * bf_hi(u.z);
        aA[6] = ddA * bf_lo(u.w); aA[7] = ddA * bf_hi(u.w);
    }
    if (vB) {
        ddB = dinv[nodeB];
        uint4 u = m4[(size_t)nodeB * 16 + t];
        aB[0] = ddB * bf_lo(u.x); aB[1] = ddB * bf_hi(u.x);
        aB[2] = ddB * bf_lo(u.y); aB[3] = ddB * bf_hi(u.y);
        aB[4] = ddB * bf_lo(u.z); aB[5] = ddB * bf_hi(u.z);
        aB[6] = ddB * bf_lo(u.w); aB[7] = ddB * bf_hi(u.w);
    }
    {
        int pA = rs[pnlA], lA = lens[pnlA];
        int pB = rs[pnlB], lB = lens[pnlB];
        dual_gather<true>(m4, csr, dinv, pA, pA + max(lA, 0),
                          pB, pB + max(lB, 0), t, aA, aB);
    }
    {
        float4 b0 = *(const float4*)&bias[t * 8];
        float4 b1 = *(const float4*)&bias[t * 8 + 4];
        float bb[8] = {b0.x, b0.y, b0.z, b0.w, b1.x, b1.y, b1.z, b1.w};
        unsigned short hvA[8], hvB[8];
#pragma unroll
        for (int j = 0; j < 8; ++j) {
            hvA[j] = vA ? f2bf_rne(fmaxf(fmaf(ddA, aA[j], bb[j]), 0.f)) : (unsigned short)0;
            hvB[j] = vB ? f2bf_rne(fmaxf(fmaf(ddB, aB[j], bb[j]), 0.f)) : (unsigned short)0;
        }
        *(uint4*)&hbuf[pnlA][t * 8] = *(uint4*)hvA;
        *(uint4*)&hbuf[pnlB][t * 8] = *(uint4*)hvB;
    }
    __syncthreads();

    // ---- gemm phase: each wave does 2 column tiles x 2 row tiles, all 4 kt ----
    int w = threadIdx.x >> 6, L = threadIdx.x & 63;
    int lm = L & 15, lq = L >> 4;
#pragma unroll
    for (int rt = 0; rt < 2; ++rt) {
        f32x4 acc2[2];
        acc2[0] = (f32x4)(0.f);
        acc2[1] = (f32x4)(0.f);
#pragma unroll
        for (int kt = 0; kt < 4; ++kt) {
            bfrag a = *(const bfrag*)&hbuf[rt * 16 + lm][kt * 32 + lq * 8];
#pragma unroll
            for (int q2 = 0; q2 < 2; ++q2) {
                int nt = w * 2 + q2;
                int o = ((kt * 8 + nt) * 64 + L) * 8;
                bfrag wh = *(const bfrag*)&whi[o];
                bfrag wl = *(const bfrag*)&wlo[o];
                acc2[q2] = __builtin_amdgcn_mfma_f32_16x16x32_bf16(a, wh, acc2[q2], 0, 0, 0);
                acc2[q2] = __builtin_amdgcn_mfma_f32_16x16x32_bf16(a, wl, acc2[q2], 0, 0, 0);
            }
        }
        // C/D layout: col(in tile)=lane&15, row=(lane>>4)*4+i; logical col = lm*8+nt
#pragma unroll
        for (int q2 = 0; q2 < 2; ++q2) {
            int nt = w * 2 + q2;
#pragma unroll
            for (int i = 0; i < 4; ++i)
                cbuf[rt * 16 + lq * 4 + i][lm * 8 + nt] = acc2[q2][i];
        }
    }
    __syncthreads();

    // ---- repack + pre-scale by dinv + round + store (original node order) ----
    int nl = threadIdx.x >> 4;
#pragma unroll
    for (int half = 0; half < 2; ++half) {
        int r = half * 16 + nl;
        int node_e = blockIdx.x * 32 + r;
        if (node_e < n) {
            float dde = dinv[node_e];
            float4 r0 = *(const float4*)&cbuf[r][t * 8];
            float4 r1 = *(const float4*)&cbuf[r][t * 8 + 4];
            unsigned short ev[8];
            ev[0] = f2bf_rne(dde * r0.x); ev[1] = f2bf_rne(dde * r0.y);
            ev[2] = f2bf_rne(dde * r0.z); ev[3] = f2bf_rne(dde * r0.w);
            ev[4] = f2bf_rne(dde * r1.x); ev[5] = f2bf_rne(dde * r1.y);
            ev[6] = f2bf_rne(dde * r1.z); ev[7] = f2bf_rne(dde * r1.w);
            out_m[(size_t)node_e * 16 + t] = *(uint4*)ev;
        }
    }
}

// ---------------- agg layer 2 fused with global max pool ----------------
// m2 rows pre-scaled by dinv[src] -> pure-add gather; dual-node quarters.
__global__ __launch_bounds__(256) void agg_pool_kernel(const uint4* __restrict__ m4,
                                                       const int* __restrict__ rowstart,
                                                       const int* __restrict__ csr,
                                                       const float* __restrict__ dinv,
                                                       const float* __restrict__ bias,
                                                       const int* __restrict__ batch,
                                                       unsigned int* __restrict__ g, int n) {
    __shared__ float smx[32][HDIM];
    __shared__ int sgid[32];
    __shared__ int lens[32];
    __shared__ int rs[32];
    __shared__ int perm[32];
    int t = threadIdx.x & 15;
    int qid = threadIdx.x >> 4;

    degree_perm32(rowstart, lens, rs, perm, n);
    int pnlA = perm[2 * qid], pnlB = perm[2 * qid + 1];
    int nodeA = blockIdx.x * 32 + pnlA;
    int nodeB = blockIdx.x * 32 + pnlB;
    bool vA = nodeA < n, vB = nodeB < n;

    float aA[8] = {0, 0, 0, 0, 0, 0, 0, 0};
    float aB[8] = {0, 0, 0, 0, 0, 0, 0, 0};
    float ddA = 0.f, ddB = 0.f;
    if (vA) {
        ddA = dinv[nodeA];
        uint4 u = m4[(size_t)nodeA * 16 + t];
        aA[0] = bf_lo(u.x); aA[1] = bf_hi(u.x);
        aA[2] = bf_lo(u.y); aA[3] = bf_hi(u.y);
        aA[4] = bf_lo(u.z); aA[5] = bf_hi(u.z);
        aA[6] = bf_lo(u.w); aA[7] = bf_hi(u.w);
    }
    if (vB) {
        ddB = dinv[nodeB];
        uint4 u = m4[(size_t)nodeB * 16 + t];
        aB[0] = bf_lo(u.x); aB[1] = bf_hi(u.x);
        aB[2] = bf_lo(u.y); aB[3] = bf_hi(u.y);
        aB[4] = bf_lo(u.z); aB[5] = bf_hi(u.z);
        aB[6] = bf_lo(u.w); aB[7] = bf_hi(u.w);
    }
    {
        int pA = rs[pnlA], lA = lens[pnlA];
        int pB = rs[pnlB], lB = lens[pnlB];
        dual_gather<false>(m4, csr, dinv, pA, pA + max(lA, 0),
                           pB, pB + max(lB, 0), t, aA, aB);
    }
    {
        float4 b0 = *(const float4*)&bias[t * 8];
        float4 b1 = *(const float4*)&bias[t * 8 + 4];
        float bb[8] = {b0.x, b0.y, b0.z, b0.w, b1.x, b1.y, b1.z, b1.w};
        if (vA) {
            float4 r0, r1;
            r0.x = fmaxf(fmaf(ddA, aA[0], bb[0]), 0.f);
            r0.y = fmaxf(fmaf(ddA, aA[1], bb[1]), 0.f);
            r0.z = fmaxf(fmaf(ddA, aA[2], bb[2]), 0.f);
            r0.w = fmaxf(fmaf(ddA, aA[3], bb[3]), 0.f);
            r1.x = fmaxf(fmaf(ddA, aA[4], bb[4]), 0.f);
            r1.y = fmaxf(fmaf(ddA, aA[5], bb[5]), 0.f);
            r1.z = fmaxf(fmaf(ddA, aA[6], bb[6]), 0.f);
            r1.w = fmaxf(fmaf(ddA, aA[7], bb[7]), 0.f);
            *(float4*)&smx[pnlA][t * 8] = r0;
            *(float4*)&smx[pnlA][t * 8 + 4] = r1;
        }
        if (vB) {
            float4 r0, r1;
            r0.x = fmaxf(fmaf(ddB, aB[0], bb[0]), 0.f);
            r0.y = fmaxf(fmaf(ddB, aB[1], bb[1]), 0.f);
            r0.z = fmaxf(fmaf(ddB, aB[2], bb[2]), 0.f);
            r0.w = fmaxf(fmaf(ddB, aB[3], bb[3]), 0.f);
            r1.x = fmaxf(fmaf(ddB, aB[4], bb[4]), 0.f);
            r1.y = fmaxf(fmaf(ddB, aB[5], bb[5]), 0.f);
            r1.z = fmaxf(fmaf(ddB, aB[6], bb[6]), 0.f);
            r1.w = fmaxf(fmaf(ddB, aB[7], bb[7]), 0.f);
            *(float4*)&smx[pnlB][t * 8] = r0;
            *(float4*)&smx[pnlB][t * 8 + 4] = r1;
        }
    }
    if (t == 0) {
        sgid[pnlA] = vA ? batch[nodeA] : -1;
        sgid[pnlB] = vB ? batch[nodeB] : -1;
    }
    __syncthreads();
    // smx/sgid indexed by original node order -> batch runs stay contiguous.
    if (threadIdx.x < HDIM) {
        int c = threadIdx.x;
        int curg = -1;
        float run = 0.f;
#pragma unroll
        for (int r = 0; r < 32; ++r) {
            int gg = sgid[r];
            if (gg < 0) continue;
            if (gg != curg) {
                if (curg >= 0) atomicMax(&g[curg * HDIM + c], __float_as_uint(run));
                curg = gg;
                run = smx[r][c];
            } else {
                run = fmaxf(run, smx[r][c]);
            }
        }
        if (curg >= 0) atomicMax(&g[curg * HDIM + c], __float_as_uint(run));
    }
}

// ---------------- MLP head + log_softmax ----------------
__global__ __launch_bounds__(128) void mlp_kernel(const unsigned int* __restrict__ gbits,
                                                  const float* __restrict__ W3,
                                                  const float* __restrict__ b3,
                                                  const float* __restrict__ W4,
                                                  const float* __restrict__ b4,
                                                  float* __restrict__ out) {
    __shared__ float gs[HDIM];
    __shared__ float r0[HDIM];
    __shared__ float r1[HDIM];
    int j = threadIdx.x;
    int b = blockIdx.x;
    gs[j] = __uint_as_float(gbits[b * HDIM + j]);
    __syncthreads();
    float acc = b3[j];
#pragma unroll 8
    for (int k = 0; k < HDIM; ++k) acc = fmaf(gs[k], W3[k * HDIM + j], acc);
    float z = fmaxf(acc, 0.f);
    r0[j] = z * W4[j * 2 + 0];
    r1[j] = z * W4[j * 2 + 1];
    __syncthreads();
    for (int off = 64; off > 0; off >>= 1) {
        if (j < off) {
            r0[j] += r0[j + off];
            r1[j] += r1[j + off];
        }
        __syncthreads();
    }
    if (j == 0) {
        float l0 = r0[0] + b4[0];
        float l1 = r1[0] + b4[1];
        float mx = fmaxf(l0, l1);
        float lse = mx + logf(expf(l0 - mx) + expf(l1 - mx));
        out[b * 2 + 0] = l0 - lse;
        out[b * 2 + 1] = l1 - lse;
    }
}

extern "C" void kernel_launch(void* const* d_in, const int* in_sizes, int n_in,
                              void* d_out, int out_size, void* d_ws, size_t ws_size,
                              hipStream_t stream) {
    const float* x  = (const float*)d_in[0];
    const float* W1 = (const float*)d_in[1];
    const float* b1 = (const float*)d_in[2];
    const float* W2 = (const float*)d_in[3];
    const float* b2 = (const float*)d_in[4];
    const float* W3 = (const float*)d_in[5];
    const float* b3 = (const float*)d_in[6];
    const float* W4 = (const float*)d_in[7];
    const float* b4 = (const float*)d_in[8];
    const int* ei    = (const int*)d_in[9];
    const int* batch = (const int*)d_in[10];

    const int N = in_sizes[0] / HDIM;   // 50000
    const int E = in_sizes[9] / 2;      // 640000
    const int G = out_size / 2;         // 64
    const int* src = ei;
    const int* dst = ei + E;

    const int nbuck = (N + 255) >> 8;        // 196 (must be <= 256)
    const int nscan = nbuck * NBLK;          // 50176
    const int chunk = (E + NBLK - 1) / NBLK; // 2500

    // ---- workspace layout (16B-aligned blocks) ----
    const int Nr = ((N + 63) / 64) * 64;
    char* wsb = (char*)d_ws;
    size_t o = 0;
    unsigned int* g = (unsigned int*)(wsb + o); o += (size_t)G * HDIM * 4;
    size_t zero_bytes = o;                 // only g needs zeroing
    int* hist = (int*)(wsb + o);           o += (size_t)nscan * 4;
    int* hscan = (int*)(wsb + o);          o += (size_t)nscan * 4;
    int* sums = (int*)(wsb + o);           o += 256 * 4;
    int* rowstart = (int*)(wsb + o);       o += (size_t)(Nr + 64) * 4;
    float* dinv = (float*)(wsb + o);       o += (size_t)Nr * 4;
    int2* sorted = (int2*)(wsb + o);       o += (size_t)E * 8;
    int* csr = (int*)(wsb + o);            o += (size_t)E * 4;
    unsigned short* wf1h = (unsigned short*)(wsb + o); o += (size_t)HDIM * HDIM * 2;
    unsigned short* wf1l = (unsigned short*)(wsb + o); o += (size_t)HDIM * HDIM * 2;
    unsigned short* wf2h = (unsigned short*)(wsb + o); o += (size_t)HDIM * HDIM * 2;
    unsigned short* wf2l = (unsigned short*)(wsb + o); o += (size_t)HDIM * HDIM * 2;
    unsigned short* m = (unsigned short*)(wsb + o);    o += (size_t)Nr * HDIM * 2;
    unsigned short* m2 = (unsigned short*)(wsb + o);   o += (size_t)Nr * HDIM * 2;
    (void)ws_size; (void)n_in;

    (void)hipMemsetAsync(d_ws, 0, zero_bytes, stream);

    int sblocks = (nscan + SCAN_B - 1) / SCAN_B;   // 196 (<= 256 required)
    int gemm_blocks = (N + GBM - 1) / GBM;         // 782
    int agg_blocks = (N + 31) / 32;                // 1563

    // K1: hist || wfrag  (independent)
    mega1_kernel<<<NBLK + 128, 256, 0, stream>>>(dst, hist, E, chunk, nbuck,
                                                 W1, W2, wf1h, wf1l, wf2h, wf2l);
    // K2: scan of hist matrix (bucket-major) -> hscan exclusive (2 dispatches)
    scan1_kernel<<<sblocks, SCAN_B, 0, stream>>>(hist, hscan, sums, nscan);
    scan3_kernel<<<sblocks, SCAN_B, 0, stream>>>(hist, hscan, sums, nscan);
    // K3: scatter (bucket sort) || gemm layer 1
    mega3_kernel<<<NBLK + gemm_blocks, 256, 0, stream>>>(src, dst, hscan, sorted,
                                                         E, chunk, nbuck,
                                                         x, wf1h, wf1l, m, N);
    // K4: per-bucket CSR build (rowstart, dinv, csr)
    csr_kernel<<<nbuck, 256, 0, stream>>>(sorted, hscan, rowstart, dinv, csr, N, E, nbuck);
    // K5: fused agg(layer1) + gemm(layer2) -> m2 (dinv-pre-scaled)
    agg_gemm_kernel<<<agg_blocks, 256, 0, stream>>>((const uint4*)m, rowstart, csr,
                                                    dinv, b1, wf2h, wf2l,
                                                    (uint4*)m2, N);
    // K6: agg layer 2 + global max pool
    agg_pool_kernel<<<agg_blocks, 256, 0, stream>>>((const uint4*)m2, rowstart, csr,
                                                    dinv, b2, batch, g, N);
    // K7: MLP head + log_softmax
    mlp_kernel<<<G, 128, 0, stream>>>(g, W3, b3, W4, b4, (float*)d_out);
}

// Round 6
// 205.109 us; speedup vs baseline: 1.0552x; 1.0247x over previous
//
#include <hip/hip_runtime.h>
#include <hip/hip_bf16.h>
#include <math.h>

// ---------------- constants ----------------
#define HDIM 128
#define SCAN_B 256
#define NBLK 256          // edge blocks for hist/scatter passes

typedef short bfrag __attribute__((ext_vector_type(8)));   // 8 bf16 (4 VGPRs)
typedef float f32x4 __attribute__((ext_vector_type(4)));   // 4 fp32 acc

__device__ inline unsigned short f2bf_rne(float x) {
    unsigned u = __float_as_uint(x);
    u = (u + 0x7fffu + ((u >> 16) & 1u)) >> 16;
    return (unsigned short)u;
}
__device__ inline float bf_lo(unsigned u) { return __uint_as_float(u << 16); }
__device__ inline float bf_hi(unsigned u) { return __uint_as_float(u & 0xffff0000u); }

// ---------------- device bodies ----------------

// Pass A: per-block LDS coarse histogram (dst>>8); no global atomics.
__device__ inline void hist_body(int b, const int* __restrict__ dst,
                                 int* __restrict__ hist, int E, int chunk, int nbuck) {
    __shared__ int hl[256];
    int t = threadIdx.x;
    hl[t] = 0;
    __syncthreads();
    int start = b * chunk, end = min(E, start + chunk);
    for (int e = start + t; e < end; e += 256) atomicAdd(&hl[dst[e] >> 8], 1);
    __syncthreads();
    if (t < nbuck) hist[t * NBLK + b] = hl[t];
}

// W -> fragment-ordered bf16 hi/lo, column-permuted: physical slot (nt, lm)
// carries logical column n_l = lm*8 + nt (so epilogue stores are 16B packed).
__device__ inline void wfrag_body(int b, const float* __restrict__ W1,
                                  const float* __restrict__ W2,
                                  unsigned short* __restrict__ w1h,
                                  unsigned short* __restrict__ w1l,
                                  unsigned short* __restrict__ w2h,
                                  unsigned short* __restrict__ w2l) {
    const float* W = (b < 64) ? W1 : W2;
    unsigned short* whi = (b < 64) ? w1h : w2h;
    unsigned short* wlo = (b < 64) ? w1l : w2l;
    int idx = (b & 63) * 256 + threadIdx.x;     // 0..16383
    int k = idx >> 7;
    int n = idx & 127;
    int kt = k >> 5, q = (k >> 3) & 3, j = k & 7;
    int lm = n >> 3, nt = n & 7;
    int lane = q * 16 + lm;
    int o = ((kt * 8 + nt) * 64 + lane) * 8 + j;
    float x = W[idx];
    unsigned short hb = f2bf_rne(x);
    float hf = __uint_as_float(((unsigned)hb) << 16);
    unsigned short lb = f2bf_rne(x - hf);
    whi[o] = hb;
    wlo[o] = lb;
}

// Pass C: scatter edges into bucket-sorted order via LDS cursors (no global atomics).
__device__ inline void scatter_body(int b, const int* __restrict__ srcv,
                                    const int* __restrict__ dstv,
                                    const int* __restrict__ hscan,
                                    int2* __restrict__ sorted,
                                    int E, int chunk, int nbuck) {
    __shared__ int cur[256];
    int t = threadIdx.x;
    if (t < nbuck) cur[t] = hscan[t * NBLK + b];
    __syncthreads();
    int start = b * chunk, end = min(E, start + chunk);
    for (int e = start + t; e < end; e += 256) {
        int d = dstv[e];
        int pos = atomicAdd(&cur[d >> 8], 1);
        sorted[pos] = make_int2(srcv[e], d);
    }
}

// MFMA GEMM (fp32 A), 64-row tiles, split 3-MFMA: C ~= Ah*Wh + Al*Wh + Ah*Wl
#define GBM 64
__device__ inline void gemm_f32_body(int b, const float* __restrict__ A,
                                     const unsigned short* __restrict__ whi,
                                     const unsigned short* __restrict__ wlo,
                                     unsigned short* __restrict__ C, int Nrows) {
    int tid = threadIdx.x;
    int w = tid >> 6, L = tid & 63;
    int lm = L & 15, lq = L >> 4;
    int row0 = b * GBM + w * 16;

    f32x4 acc[8];
#pragma unroll
    for (int nt = 0; nt < 8; ++nt) acc[nt] = (f32x4)(0.f);

#pragma unroll
    for (int kt = 0; kt < 4; ++kt) {
        int gr = row0 + lm;
        float4 v0 = make_float4(0.f, 0.f, 0.f, 0.f);
        float4 v1 = v0;
        if (gr < Nrows) {
            const float* p = &A[(size_t)gr * HDIM + kt * 32 + lq * 8];
            v0 = *(const float4*)p;
            v1 = *(const float4*)(p + 4);
        }
        float xv[8] = {v0.x, v0.y, v0.z, v0.w, v1.x, v1.y, v1.z, v1.w};
        bfrag ah, al;
#pragma unroll
        for (int j = 0; j < 8; ++j) {
            float x = xv[j];
            unsigned short hb = f2bf_rne(x);
            float hf = __uint_as_float(((unsigned)hb) << 16);
            unsigned short lb = f2bf_rne(x - hf);
            ah[j] = (short)hb;
            al[j] = (short)lb;
        }
#pragma unroll
        for (int nt = 0; nt < 8; ++nt) {
            int o = ((kt * 8 + nt) * 64 + L) * 8;
            bfrag wh = *(const bfrag*)&whi[o];
            bfrag wl = *(const bfrag*)&wlo[o];
            acc[nt] = __builtin_amdgcn_mfma_f32_16x16x32_bf16(ah, wh, acc[nt], 0, 0, 0);
            acc[nt] = __builtin_amdgcn_mfma_f32_16x16x32_bf16(al, wh, acc[nt], 0, 0, 0);
            acc[nt] = __builtin_amdgcn_mfma_f32_16x16x32_bf16(ah, wl, acc[nt], 0, 0, 0);
        }
    }

#pragma unroll
    for (int i = 0; i < 4; ++i) {
        int gr = row0 + lq * 4 + i;
        if (gr < Nrows) {
            bfrag e;
#pragma unroll
            for (int nt = 0; nt < 8; ++nt) e[nt] = (short)f2bf_rne(acc[nt][i]);
            *(bfrag*)&C[(size_t)gr * HDIM + lm * 8] = e;
        }
    }
}

// ---------------- megakernel 1: hist || wfrag ----------------
__global__ __launch_bounds__(256) void mega1_kernel(const int* __restrict__ dst,
                                                    int* __restrict__ hist, int E,
                                                    int chunk, int nbuck,
                                                    const float* __restrict__ W1,
                                                    const float* __restrict__ W2,
                                                    unsigned short* __restrict__ w1h,
                                                    unsigned short* __restrict__ w1l,
                                                    unsigned short* __restrict__ w2h,
                                                    unsigned short* __restrict__ w2l) {
    int b = blockIdx.x;
    if (b < NBLK) hist_body(b, dst, hist, E, chunk, nbuck);
    else wfrag_body(b - NBLK, W1, W2, w1h, w1l, w2h, w2l);
}

// ---------------- megakernel 3: scatter || gemm_f32(layer1) ----------------
__global__ __launch_bounds__(256) void mega3_kernel(const int* __restrict__ srcv,
                                                    const int* __restrict__ dstv,
                                                    const int* __restrict__ hscan,
                                                    int2* __restrict__ sorted,
                                                    int E, int chunk, int nbuck,
                                                    const float* __restrict__ A,
                                                    const unsigned short* __restrict__ whi,
                                                    const unsigned short* __restrict__ wlo,
                                                    unsigned short* __restrict__ C, int Nrows) {
    int b = blockIdx.x;
    if (b < NBLK) scatter_body(b, srcv, dstv, hscan, sorted, E, chunk, nbuck);
    else gemm_f32_body(b - NBLK, A, whi, wlo, C, Nrows);
}

// ---------------- scan phase 1: per-block inclusive scan ----------------
__global__ __launch_bounds__(SCAN_B) void scan1_kernel(const int* __restrict__ in,
                                                       int* __restrict__ out,
                                                       int* __restrict__ sums, int n) {
    __shared__ int s[SCAN_B];
    int t = threadIdx.x;
    int idx = blockIdx.x * SCAN_B + t;
    int v = (idx < n) ? in[idx] : 0;
    s[t] = v;
    __syncthreads();
    for (int off = 1; off < SCAN_B; off <<= 1) {
        int x = (t >= off) ? s[t - off] : 0;
        __syncthreads();
        s[t] += x;
        __syncthreads();
    }
    if (idx < n) out[idx] = s[t];
    if (t == SCAN_B - 1) sums[blockIdx.x] = s[t];
}

// ---------------- scan phase 2+3 fused ----------------
__global__ __launch_bounds__(SCAN_B) void scan3_kernel(const int* __restrict__ in,
                                                       int* __restrict__ inout,
                                                       const int* __restrict__ sums,
                                                       int n) {
    __shared__ int s[SCAN_B];
    int t = threadIdx.x;
    int b = blockIdx.x;                 // gridDim.x <= 256 required
    s[t] = (t < b) ? sums[t] : 0;
    __syncthreads();
    for (int off = SCAN_B / 2; off > 0; off >>= 1) {
        if (t < off) s[t] += s[t + off];
        __syncthreads();
    }
    int base = s[0];
    int idx = b * SCAN_B + t;
    if (idx < n) inout[idx] = inout[idx] - in[idx] + base;
}

// ---------------- Pass D: per-bucket CSR build (LDS atomics only) ----------------
__global__ __launch_bounds__(256) void csr_kernel(const int2* __restrict__ sorted,
                                                  const int* __restrict__ hscan,
                                                  int* __restrict__ rowstart,
                                                  float* __restrict__ dinv,
                                                  int* __restrict__ csr,
                                                  int N, int E, int nbuck) {
    __shared__ int cnt[256];
    __shared__ int s[256];
    __shared__ int cur[256];
    int b = blockIdx.x;
    int t = threadIdx.x;
    int start = hscan[b * NBLK];
    int end = (b + 1 < nbuck) ? hscan[(b + 1) * NBLK] : E;
    cnt[t] = 0;
    __syncthreads();
    for (int e = start + t; e < end; e += 256)
        atomicAdd(&cnt[sorted[e].y & 255], 1);
    __syncthreads();
    int v = cnt[t];
    s[t] = v;
    __syncthreads();
    for (int off = 1; off < 256; off <<= 1) {
        int x = (t >= off) ? s[t - off] : 0;
        __syncthreads();
        s[t] += x;
        __syncthreads();
    }
    int excl = s[t] - v;
    int node = b * 256 + t;
    if (node < N) {
        rowstart[node] = start + excl;
        dinv[node] = rsqrtf((float)(v + 1));   // +1 self-loop
    }
    if (b == nbuck - 1 && t == 0) rowstart[N] = E;
    cur[t] = start + excl;
    __syncthreads();
    for (int e = start + t; e < end; e += 256) {
        int2 ed = sorted[e];
        int pos = atomicAdd(&cur[ed.y & 255], 1);
        csr[pos] = ed.x;
    }
}

// ---------------- gather primitives ----------------
// WEIGHTED: acc += dinv[s] * m[s]  (layer-1 rows unscaled)
// !WEIGHTED: acc += m[s]           (layer-2 rows pre-scaled by dinv[src])
template <bool W>
__device__ inline void qacc1(float* acc, uint4 uv, float wt) {
    if (W) {
        acc[0] = fmaf(wt, bf_lo(uv.x), acc[0]);
        acc[1] = fmaf(wt, bf_hi(uv.x), acc[1]);
        acc[2] = fmaf(wt, bf_lo(uv.y), acc[2]);
        acc[3] = fmaf(wt, bf_hi(uv.y), acc[3]);
        acc[4] = fmaf(wt, bf_lo(uv.z), acc[4]);
        acc[5] = fmaf(wt, bf_hi(uv.z), acc[5]);
        acc[6] = fmaf(wt, bf_lo(uv.w), acc[6]);
        acc[7] = fmaf(wt, bf_hi(uv.w), acc[7]);
    } else {
        acc[0] += bf_lo(uv.x); acc[1] += bf_hi(uv.x);
        acc[2] += bf_lo(uv.y); acc[3] += bf_hi(uv.y);
        acc[4] += bf_lo(uv.z); acc[5] += bf_hi(uv.z);
        acc[6] += bf_lo(uv.w); acc[7] += bf_hi(uv.w);
    }
}

// 8-deep gather with one-batch-ahead INDEX prefetch (software pipeline):
// steady-state body issues rows(k)+dinv(k), then idx(k+1), then adds(k).
// The vmcnt wait before adds(k) leaves idx(k+1) in flight -> the csr-load
// stage of the 2-level dependency chain is hidden under the row-load stage.
template <bool W>
__device__ inline void qgather(const uint4* __restrict__ m4,
                               const int* __restrict__ csr,
                               const float* __restrict__ dinv,
                               int p, int pend, int t, float* acc) {
    if (p + 8 <= pend) {
        int s0 = csr[p], s1 = csr[p + 1], s2 = csr[p + 2], s3 = csr[p + 3];
        int s4 = csr[p + 4], s5 = csr[p + 5], s6 = csr[p + 6], s7 = csr[p + 7];
        p += 8;
        for (; p + 8 <= pend; p += 8) {
            // rows + weights for current batch (issue first)
            uint4 u0 = m4[(size_t)s0 * 16 + t];
            uint4 u1 = m4[(size_t)s1 * 16 + t];
            uint4 u2 = m4[(size_t)s2 * 16 + t];
            uint4 u3 = m4[(size_t)s3 * 16 + t];
            uint4 u4 = m4[(size_t)s4 * 16 + t];
            uint4 u5 = m4[(size_t)s5 * 16 + t];
            uint4 u6 = m4[(size_t)s6 * 16 + t];
            uint4 u7 = m4[(size_t)s7 * 16 + t];
            float w0 = 0.f, w1 = 0.f, w2 = 0.f, w3 = 0.f;
            float w4 = 0.f, w5 = 0.f, w6 = 0.f, w7 = 0.f;
            if (W) {
                w0 = dinv[s0]; w1 = dinv[s1]; w2 = dinv[s2]; w3 = dinv[s3];
                w4 = dinv[s4]; w5 = dinv[s5]; w6 = dinv[s6]; w7 = dinv[s7];
            }
            // next batch's indices (issued before adds; stay in flight)
            int n0 = csr[p], n1 = csr[p + 1], n2 = csr[p + 2], n3 = csr[p + 3];
            int n4 = csr[p + 4], n5 = csr[p + 5], n6 = csr[p + 6], n7 = csr[p + 7];
            qacc1<W>(acc, u0, w0); qacc1<W>(acc, u1, w1);
            qacc1<W>(acc, u2, w2); qacc1<W>(acc, u3, w3);
            qacc1<W>(acc, u4, w4); qacc1<W>(acc, u5, w5);
            qacc1<W>(acc, u6, w6); qacc1<W>(acc, u7, w7);
            s0 = n0; s1 = n1; s2 = n2; s3 = n3;
            s4 = n4; s5 = n5; s6 = n6; s7 = n7;
        }
        // drain the last full batch
        {
            uint4 u0 = m4[(size_t)s0 * 16 + t];
            uint4 u1 = m4[(size_t)s1 * 16 + t];
            uint4 u2 = m4[(size_t)s2 * 16 + t];
            uint4 u3 = m4[(size_t)s3 * 16 + t];
            uint4 u4 = m4[(size_t)s4 * 16 + t];
            uint4 u5 = m4[(size_t)s5 * 16 + t];
            uint4 u6 = m4[(size_t)s6 * 16 + t];
            uint4 u7 = m4[(size_t)s7 * 16 + t];
            float w0 = 0.f, w1 = 0.f, w2 = 0.f, w3 = 0.f;
            float w4 = 0.f, w5 = 0.f, w6 = 0.f, w7 = 0.f;
            if (W) {
                w0 = dinv[s0]; w1 = dinv[s1]; w2 = dinv[s2]; w3 = dinv[s3];
                w4 = dinv[s4]; w5 = dinv[s5]; w6 = dinv[s6]; w7 = dinv[s7];
            }
            qacc1<W>(acc, u0, w0); qacc1<W>(acc, u1, w1);
            qacc1<W>(acc, u2, w2); qacc1<W>(acc, u3, w3);
            qacc1<W>(acc, u4, w4); qacc1<W>(acc, u5, w5);
            qacc1<W>(acc, u6, w6); qacc1<W>(acc, u7, w7);
        }
    }
    if (p + 4 <= pend) {
        int s0 = csr[p], s1 = csr[p + 1], s2 = csr[p + 2], s3 = csr[p + 3];
        float w0 = 0.f, w1 = 0.f, w2 = 0.f, w3 = 0.f;
        if (W) { w0 = dinv[s0]; w1 = dinv[s1]; w2 = dinv[s2]; w3 = dinv[s3]; }
        uint4 u0 = m4[(size_t)s0 * 16 + t];
        uint4 u1 = m4[(size_t)s1 * 16 + t];
        uint4 u2 = m4[(size_t)s2 * 16 + t];
        uint4 u3 = m4[(size_t)s3 * 16 + t];
        qacc1<W>(acc, u0, w0); qacc1<W>(acc, u1, w1);
        qacc1<W>(acc, u2, w2); qacc1<W>(acc, u3, w3);
        p += 4;
    }
    if (p + 2 <= pend) {
        int s0 = csr[p], s1 = csr[p + 1];
        float w0 = 0.f, w1 = 0.f;
        if (W) { w0 = dinv[s0]; w1 = dinv[s1]; }
        uint4 u0 = m4[(size_t)s0 * 16 + t];
        uint4 u1 = m4[(size_t)s1 * 16 + t];
        qacc1<W>(acc, u0, w0); qacc1<W>(acc, u1, w1);
        p += 2;
    }
    if (p < pend) {
        int s0 = csr[p];
        float w0 = W ? dinv[s0] : 0.f;
        uint4 u0 = m4[(size_t)s0 * 16 + t];
        qacc1<W>(acc, u0, w0);
    }
}

// In-block degree sort: rank the block's 16 nodes by row length (desc) so each
// wave's 4 quarter-nodes have similar trip counts -> minimal exec-mask waste.
// Also stashes row starts/lengths in LDS. Returns permuted node-in-block.
__device__ inline int degree_perm(const int* __restrict__ rowstart,
                                  int* lens, int* rs, int* perm, int n) {
    if (threadIdx.x < 16) {
        int nn = blockIdx.x * 16 + threadIdx.x;
        int a = (nn < n) ? rowstart[nn] : 0;
        int bnd = (nn < n) ? rowstart[nn + 1] : 0;
        rs[threadIdx.x] = a;
        lens[threadIdx.x] = (nn < n) ? (bnd - a) : -1;
    }
    __syncthreads();
    if (threadIdx.x < 16) {
        int L = lens[threadIdx.x];
        int r = 0;
#pragma unroll
        for (int j = 0; j < 16; ++j) {
            int Lj = lens[j];
            r += (Lj > L || (Lj == L && j < (int)threadIdx.x)) ? 1 : 0;
        }
        perm[r] = threadIdx.x;
    }
    __syncthreads();
    return perm[threadIdx.x >> 4];
}

// ---------------- fused agg(layer1) + gemm(layer2): m2 = dinv*bf16(relu(agg)+b1)@W2 ----------------
__global__ __launch_bounds__(256) void agg_gemm_kernel(
        const uint4* __restrict__ m4,
        const int* __restrict__ rowstart,
        const int* __restrict__ csr,
        const float* __restrict__ dinv,
        const float* __restrict__ bias,
        const unsigned short* __restrict__ whi,   // W2 frags
        const unsigned short* __restrict__ wlo,
        uint4* __restrict__ out_m, int n) {
    __shared__ unsigned short hbuf[16][HDIM + 8];   // bf16 h tile (+16B pad)
    __shared__ float cbuf[16][HDIM + 4];            // fp32 C tile (+16B pad)
    __shared__ int lens[16];
    __shared__ int rs[16];
    __shared__ int perm[16];
    int t = threadIdx.x & 15;

    int pnl = degree_perm(rowstart, lens, rs, perm, n);
    int node = blockIdx.x * 16 + pnl;

    // ---- agg phase (processes node `pnl`, writes hbuf[pnl]) ----
    unsigned short hv[8] = {0, 0, 0, 0, 0, 0, 0, 0};
    if (node < n) {
        float dd = dinv[node];
        float acc[8];
        uint4 u = m4[(size_t)node * 16 + t];
        acc[0] = dd * bf_lo(u.x); acc[1] = dd * bf_hi(u.x);
        acc[2] = dd * bf_lo(u.y); acc[3] = dd * bf_hi(u.y);
        acc[4] = dd * bf_lo(u.z); acc[5] = dd * bf_hi(u.z);
        acc[6] = dd * bf_lo(u.w); acc[7] = dd * bf_hi(u.w);
        int p0 = rs[pnl];
        qgather<true>(m4, csr, dinv, p0, p0 + lens[pnl], t, acc);
        float4 b0 = *(const float4*)&bias[t * 8];
        float4 b1 = *(const float4*)&bias[t * 8 + 4];
        float bb[8] = {b0.x, b0.y, b0.z, b0.w, b1.x, b1.y, b1.z, b1.w};
#pragma unroll
        for (int j = 0; j < 8; ++j)
            hv[j] = f2bf_rne(fmaxf(fmaf(dd, acc[j], bb[j]), 0.f));
    }
    *(uint4*)&hbuf[pnl][t * 8] = *(uint4*)hv;
    __syncthreads();

    // ---- gemm phase: each wave does 2 column tiles, all 4 kt ----
    int w = threadIdx.x >> 6, L = threadIdx.x & 63;
    int lm = L & 15, lq = L >> 4;
    f32x4 acc2[2];
    acc2[0] = (f32x4)(0.f);
    acc2[1] = (f32x4)(0.f);
#pragma unroll
    for (int kt = 0; kt < 4; ++kt) {
        bfrag a = *(const bfrag*)&hbuf[lm][kt * 32 + lq * 8];
#pragma unroll
        for (int q2 = 0; q2 < 2; ++q2) {
            int nt = w * 2 + q2;
            int o = ((kt * 8 + nt) * 64 + L) * 8;
            bfrag wh = *(const bfrag*)&whi[o];
            bfrag wl = *(const bfrag*)&wlo[o];
            acc2[q2] = __builtin_amdgcn_mfma_f32_16x16x32_bf16(a, wh, acc2[q2], 0, 0, 0);
            acc2[q2] = __builtin_amdgcn_mfma_f32_16x16x32_bf16(a, wl, acc2[q2], 0, 0, 0);
        }
    }
    // C/D layout: col(in tile)=lane&15, row=(lane>>4)*4+i; logical col = lm*8+nt
#pragma unroll
    for (int q2 = 0; q2 < 2; ++q2) {
        int nt = w * 2 + q2;
#pragma unroll
        for (int i = 0; i < 4; ++i) cbuf[lq * 4 + i][lm * 8 + nt] = acc2[q2][i];
    }
    __syncthreads();

    // ---- repack + pre-scale by dinv + round + store (original node order) ----
    int nl = threadIdx.x >> 4;
    int node_e = blockIdx.x * 16 + nl;
    if (node_e < n) {
        float dde = dinv[node_e];
        float4 r0 = *(const float4*)&cbuf[nl][t * 8];
        float4 r1 = *(const float4*)&cbuf[nl][t * 8 + 4];
        unsigned short ev[8];
        ev[0] = f2bf_rne(dde * r0.x); ev[1] = f2bf_rne(dde * r0.y);
        ev[2] = f2bf_rne(dde * r0.z); ev[3] = f2bf_rne(dde * r0.w);
        ev[4] = f2bf_rne(dde * r1.x); ev[5] = f2bf_rne(dde * r1.y);
        ev[6] = f2bf_rne(dde * r1.z); ev[7] = f2bf_rne(dde * r1.w);
        out_m[(size_t)node_e * 16 + t] = *(uint4*)ev;
    }
}

// ---------------- agg layer 2 fused with global max pool ----------------
// m2 rows pre-scaled by dinv[src] -> pure-add gather; degree-sorted waves.
__global__ __launch_bounds__(256) void agg_pool_kernel(const uint4* __restrict__ m4,
                                                       const int* __restrict__ rowstart,
                                                       const int* __restrict__ csr,
                                                       const float* __restrict__ dinv,
                                                       const float* __restrict__ bias,
                                                       const int* __restrict__ batch,
                                                       unsigned int* __restrict__ g, int n) {
    __shared__ float smx[16][HDIM];
    __shared__ int sgid[16];
    __shared__ int lens[16];
    __shared__ int rs[16];
    __shared__ int perm[16];
    int t = threadIdx.x & 15;

    int pnl = degree_perm(rowstart, lens, rs, perm, n);
    int node = blockIdx.x * 16 + pnl;
    bool valid = node < n;
    if (valid) {
        float dd = dinv[node];
        float acc[8];
        uint4 u = m4[(size_t)node * 16 + t];
        acc[0] = bf_lo(u.x); acc[1] = bf_hi(u.x);
        acc[2] = bf_lo(u.y); acc[3] = bf_hi(u.y);
        acc[4] = bf_lo(u.z); acc[5] = bf_hi(u.z);
        acc[6] = bf_lo(u.w); acc[7] = bf_hi(u.w);
        int p0 = rs[pnl];
        qgather<false>(m4, csr, dinv, p0, p0 + lens[pnl], t, acc);
        float4 b0 = *(const float4*)&bias[t * 8];
        float4 b1 = *(const float4*)&bias[t * 8 + 4];
        float4 r0, r1;
        r0.x = fmaxf(fmaf(dd, acc[0], b0.x), 0.f);
        r0.y = fmaxf(fmaf(dd, acc[1], b0.y), 0.f);
        r0.z = fmaxf(fmaf(dd, acc[2], b0.z), 0.f);
        r0.w = fmaxf(fmaf(dd, acc[3], b0.w), 0.f);
        r1.x = fmaxf(fmaf(dd, acc[4], b1.x), 0.f);
        r1.y = fmaxf(fmaf(dd, acc[5], b1.y), 0.f);
        r1.z = fmaxf(fmaf(dd, acc[6], b1.z), 0.f);
        r1.w = fmaxf(fmaf(dd, acc[7], b1.w), 0.f);
        *(float4*)&smx[pnl][t * 8] = r0;
        *(float4*)&smx[pnl][t * 8 + 4] = r1;
    }
    if (t == 0) sgid[pnl] = valid ? batch[node] : -1;
    __syncthreads();
    // smx/sgid indexed by original node order -> batch runs stay contiguous.
    if (threadIdx.x < HDIM) {
        int c = threadIdx.x;
        int curg = -1;
        float run = 0.f;
#pragma unroll
        for (int r = 0; r < 16; ++r) {
            int gg = sgid[r];
            if (gg < 0) continue;
            if (gg != curg) {
                if (curg >= 0) atomicMax(&g[curg * HDIM + c], __float_as_uint(run));
                curg = gg;
                run = smx[r][c];
            } else {
                run = fmaxf(run, smx[r][c]);
            }
        }
        if (curg >= 0) atomicMax(&g[curg * HDIM + c], __float_as_uint(run));
    }
}

// ---------------- MLP head + log_softmax ----------------
__global__ __launch_bounds__(128) void mlp_kernel(const unsigned int* __restrict__ gbits,
                                                  const float* __restrict__ W3,
                                                  const float* __restrict__ b3,
                                                  const float* __restrict__ W4,
                                                  const float* __restrict__ b4,
                                                  float* __restrict__ out) {
    __shared__ float gs[HDIM];
    __shared__ float r0[HDIM];
    __shared__ float r1[HDIM];
    int j = threadIdx.x;
    int b = blockIdx.x;
    gs[j] = __uint_as_float(gbits[b * HDIM + j]);
    __syncthreads();
    float acc = b3[j];
#pragma unroll 8
    for (int k = 0; k < HDIM; ++k) acc = fmaf(gs[k], W3[k * HDIM + j], acc);
    float z = fmaxf(acc, 0.f);
    r0[j] = z * W4[j * 2 + 0];
    r1[j] = z * W4[j * 2 + 1];
    __syncthreads();
    for (int off = 64; off > 0; off >>= 1) {
        if (j < off) {
            r0[j] += r0[j + off];
            r1[j] += r1[j + off];
        }
        __syncthreads();
    }
    if (j == 0) {
        float l0 = r0[0] + b4[0];
        float l1 = r1[0] + b4[1];
        float mx = fmaxf(l0, l1);
        float lse = mx + logf(expf(l0 - mx) + expf(l1 - mx));
        out[b * 2 + 0] = l0 - lse;
        out[b * 2 + 1] = l1 - lse;
    }
}

extern "C" void kernel_launch(void* const* d_in, const int* in_sizes, int n_in,
                              void* d_out, int out_size, void* d_ws, size_t ws_size,
                              hipStream_t stream) {
    const float* x  = (const float*)d_in[0];
    const float* W1 = (const float*)d_in[1];
    const float* b1 = (const float*)d_in[2];
    const float* W2 = (const float*)d_in[3];
    const float* b2 = (const float*)d_in[4];
    const float* W3 = (const float*)d_in[5];
    const float* b3 = (const float*)d_in[6];
    const float* W4 = (const float*)d_in[7];
    const float* b4 = (const float*)d_in[8];
    const int* ei    = (const int*)d_in[9];
    const int* batch = (const int*)d_in[10];

    const int N = in_sizes[0] / HDIM;   // 50000
    const int E = in_sizes[9] / 2;      // 640000
    const int G = out_size / 2;         // 64
    const int* src = ei;
    const int* dst = ei + E;

    const int nbuck = (N + 255) >> 8;        // 196 (must be <= 256)
    const int nscan = nbuck * NBLK;          // 50176
    const int chunk = (E + NBLK - 1) / NBLK; // 2500

    // ---- workspace layout (16B-aligned blocks) ----
    const int Nr = ((N + 63) / 64) * 64;
    char* wsb = (char*)d_ws;
    size_t o = 0;
    unsigned int* g = (unsigned int*)(wsb + o); o += (size_t)G * HDIM * 4;
    size_t zero_bytes = o;                 // only g needs zeroing
    int* hist = (int*)(wsb + o);           o += (size_t)nscan * 4;
    int* hscan = (int*)(wsb + o);          o += (size_t)nscan * 4;
    int* sums = (int*)(wsb + o);           o += 256 * 4;
    int* rowstart = (int*)(wsb + o);       o += (size_t)(Nr + 64) * 4;
    float* dinv = (float*)(wsb + o);       o += (size_t)Nr * 4;
    int2* sorted = (int2*)(wsb + o);       o += (size_t)E * 8;
    int* csr = (int*)(wsb + o);            o += (size_t)E * 4;
    unsigned short* wf1h = (unsigned short*)(wsb + o); o += (size_t)HDIM * HDIM * 2;
    unsigned short* wf1l = (unsigned short*)(wsb + o); o += (size_t)HDIM * HDIM * 2;
    unsigned short* wf2h = (unsigned short*)(wsb + o); o += (size_t)HDIM * HDIM * 2;
    unsigned short* wf2l = (unsigned short*)(wsb + o); o += (size_t)HDIM * HDIM * 2;
    unsigned short* m = (unsigned short*)(wsb + o);    o += (size_t)Nr * HDIM * 2;
    unsigned short* m2 = (unsigned short*)(wsb + o);   o += (size_t)Nr * HDIM * 2;
    (void)ws_size; (void)n_in;

    (void)hipMemsetAsync(d_ws, 0, zero_bytes, stream);

    int sblocks = (nscan + SCAN_B - 1) / SCAN_B;   // 196 (<= 256 required)
    int gemm_blocks = (N + GBM - 1) / GBM;         // 782
    int agg_blocks = (N + 15) / 16;                // 3125

    // K1: hist || wfrag  (independent)
    mega1_kernel<<<NBLK + 128, 256, 0, stream>>>(dst, hist, E, chunk, nbuck,
                                                 W1, W2, wf1h, wf1l, wf2h, wf2l);
    // K2: scan of hist matrix (bucket-major) -> hscan exclusive (2 dispatches)
    scan1_kernel<<<sblocks, SCAN_B, 0, stream>>>(hist, hscan, sums, nscan);
    scan3_kernel<<<sblocks, SCAN_B, 0, stream>>>(hist, hscan, sums, nscan);
    // K3: scatter (bucket sort) || gemm layer 1
    mega3_kernel<<<NBLK + gemm_blocks, 256, 0, stream>>>(src, dst, hscan, sorted,
                                                         E, chunk, nbuck,
                                                         x, wf1h, wf1l, m, N);
    // K4: per-bucket CSR build (rowstart, dinv, csr)
    csr_kernel<<<nbuck, 256, 0, stream>>>(sorted, hscan, rowstart, dinv, csr, N, E, nbuck);
    // K5: fused agg(layer1) + gemm(layer2) -> m2 (dinv-pre-scaled)
    agg_gemm_kernel<<<agg_blocks, 256, 0, stream>>>((const uint4*)m, rowstart, csr,
                                                    dinv, b1, wf2h, wf2l,
                                                    (uint4*)m2, N);
    // K6: agg layer 2 + global max pool
    agg_pool_kernel<<<agg_blocks, 256, 0, stream>>>((const uint4*)m2, rowstart, csr,
                                                    dinv, b2, batch, g, N);
    // K7: MLP head + log_softmax
    mlp_kernel<<<G, 128, 0, stream>>>(g, W3, b3, W4, b4, (float*)d_out);
}

// Round 7
// 197.554 us; speedup vs baseline: 1.0955x; 1.0382x over previous
//
#include <hip/hip_runtime.h>
#include <hip/hip_bf16.h>
#include <math.h>

// ---------------- constants ----------------
#define HDIM 128
#define SCAN_B 256
#define NBLK 256          // edge blocks for hist/scatter passes
#define BPAD 1800         // per-bucket extra CSR capacity for padding (multiple of 8)

typedef short bfrag __attribute__((ext_vector_type(8)));   // 8 bf16 (4 VGPRs)
typedef float f32x4 __attribute__((ext_vector_type(4)));   // 4 fp32 acc

__device__ inline unsigned short f2bf_rne(float x) {
    unsigned u = __float_as_uint(x);
    u = (u + 0x7fffu + ((u >> 16) & 1u)) >> 16;
    return (unsigned short)u;
}
__device__ inline float bf_lo(unsigned u) { return __uint_as_float(u << 16); }
__device__ inline float bf_hi(unsigned u) { return __uint_as_float(u & 0xffff0000u); }

// ---------------- device bodies ----------------

// Pass A: per-block LDS coarse histogram (dst>>8); no global atomics.
__device__ inline void hist_body(int b, const int* __restrict__ dst,
                                 int* __restrict__ hist, int E, int chunk, int nbuck) {
    __shared__ int hl[256];
    int t = threadIdx.x;
    hl[t] = 0;
    __syncthreads();
    int start = b * chunk, end = min(E, start + chunk);
    for (int e = start + t; e < end; e += 256) atomicAdd(&hl[dst[e] >> 8], 1);
    __syncthreads();
    if (t < nbuck) hist[t * NBLK + b] = hl[t];
}

// W -> fragment-ordered bf16 hi/lo, column-permuted: physical slot (nt, lm)
// carries logical column n_l = lm*8 + nt (so epilogue stores are 16B packed).
__device__ inline void wfrag_body(int b, const float* __restrict__ W1,
                                  const float* __restrict__ W2,
                                  unsigned short* __restrict__ w1h,
                                  unsigned short* __restrict__ w1l,
                                  unsigned short* __restrict__ w2h,
                                  unsigned short* __restrict__ w2l) {
    const float* W = (b < 64) ? W1 : W2;
    unsigned short* whi = (b < 64) ? w1h : w2h;
    unsigned short* wlo = (b < 64) ? w1l : w2l;
    int idx = (b & 63) * 256 + threadIdx.x;     // 0..16383
    int k = idx >> 7;
    int n = idx & 127;
    int kt = k >> 5, q = (k >> 3) & 3, j = k & 7;
    int lm = n >> 3, nt = n & 7;
    int lane = q * 16 + lm;
    int o = ((kt * 8 + nt) * 64 + lane) * 8 + j;
    float x = W[idx];
    unsigned short hb = f2bf_rne(x);
    float hf = __uint_as_float(((unsigned)hb) << 16);
    unsigned short lb = f2bf_rne(x - hf);
    whi[o] = hb;
    wlo[o] = lb;
}

// Pass C: scatter edges into bucket-sorted order via LDS cursors (no global atomics).
__device__ inline void scatter_body(int b, const int* __restrict__ srcv,
                                    const int* __restrict__ dstv,
                                    const int* __restrict__ hscan,
                                    int2* __restrict__ sorted,
                                    int E, int chunk, int nbuck) {
    __shared__ int cur[256];
    int t = threadIdx.x;
    if (t < nbuck) cur[t] = hscan[t * NBLK + b];
    __syncthreads();
    int start = b * chunk, end = min(E, start + chunk);
    for (int e = start + t; e < end; e += 256) {
        int d = dstv[e];
        int pos = atomicAdd(&cur[d >> 8], 1);
        sorted[pos] = make_int2(srcv[e], d);
    }
}

// MFMA GEMM (fp32 A), 64-row tiles, split 3-MFMA: C ~= Ah*Wh + Al*Wh + Ah*Wl
#define GBM 64
__device__ inline void gemm_f32_body(int b, const float* __restrict__ A,
                                     const unsigned short* __restrict__ whi,
                                     const unsigned short* __restrict__ wlo,
                                     unsigned short* __restrict__ C, int Nrows) {
    int tid = threadIdx.x;
    int w = tid >> 6, L = tid & 63;
    int lm = L & 15, lq = L >> 4;
    int row0 = b * GBM + w * 16;

    f32x4 acc[8];
#pragma unroll
    for (int nt = 0; nt < 8; ++nt) acc[nt] = (f32x4)(0.f);

#pragma unroll
    for (int kt = 0; kt < 4; ++kt) {
        int gr = row0 + lm;
        float4 v0 = make_float4(0.f, 0.f, 0.f, 0.f);
        float4 v1 = v0;
        if (gr < Nrows) {
            const float* p = &A[(size_t)gr * HDIM + kt * 32 + lq * 8];
            v0 = *(const float4*)p;
            v1 = *(const float4*)(p + 4);
        }
        float xv[8] = {v0.x, v0.y, v0.z, v0.w, v1.x, v1.y, v1.z, v1.w};
        bfrag ah, al;
#pragma unroll
        for (int j = 0; j < 8; ++j) {
            float x = xv[j];
            unsigned short hb = f2bf_rne(x);
            float hf = __uint_as_float(((unsigned)hb) << 16);
            unsigned short lb = f2bf_rne(x - hf);
            ah[j] = (short)hb;
            al[j] = (short)lb;
        }
#pragma unroll
        for (int nt = 0; nt < 8; ++nt) {
            int o = ((kt * 8 + nt) * 64 + L) * 8;
            bfrag wh = *(const bfrag*)&whi[o];
            bfrag wl = *(const bfrag*)&wlo[o];
            acc[nt] = __builtin_amdgcn_mfma_f32_16x16x32_bf16(ah, wh, acc[nt], 0, 0, 0);
            acc[nt] = __builtin_amdgcn_mfma_f32_16x16x32_bf16(al, wh, acc[nt], 0, 0, 0);
            acc[nt] = __builtin_amdgcn_mfma_f32_16x16x32_bf16(ah, wl, acc[nt], 0, 0, 0);
        }
    }

#pragma unroll
    for (int i = 0; i < 4; ++i) {
        int gr = row0 + lq * 4 + i;
        if (gr < Nrows) {
            bfrag e;
#pragma unroll
            for (int nt = 0; nt < 8; ++nt) e[nt] = (short)f2bf_rne(acc[nt][i]);
            *(bfrag*)&C[(size_t)gr * HDIM + lm * 8] = e;
        }
    }
}

// ---------------- megakernel 1: hist || wfrag ----------------
__global__ __launch_bounds__(256) void mega1_kernel(const int* __restrict__ dst,
                                                    int* __restrict__ hist, int E,
                                                    int chunk, int nbuck,
                                                    const float* __restrict__ W1,
                                                    const float* __restrict__ W2,
                                                    unsigned short* __restrict__ w1h,
                                                    unsigned short* __restrict__ w1l,
                                                    unsigned short* __restrict__ w2h,
                                                    unsigned short* __restrict__ w2l) {
    int b = blockIdx.x;
    if (b < NBLK) hist_body(b, dst, hist, E, chunk, nbuck);
    else wfrag_body(b - NBLK, W1, W2, w1h, w1l, w2h, w2l);
}

// ---------------- megakernel 3: scatter || gemm_f32(layer1) ----------------
__global__ __launch_bounds__(256) void mega3_kernel(const int* __restrict__ srcv,
                                                    const int* __restrict__ dstv,
                                                    const int* __restrict__ hscan,
                                                    int2* __restrict__ sorted,
                                                    int E, int chunk, int nbuck,
                                                    const float* __restrict__ A,
                                                    const unsigned short* __restrict__ whi,
                                                    const unsigned short* __restrict__ wlo,
                                                    unsigned short* __restrict__ C, int Nrows) {
    int b = blockIdx.x;
    if (b < NBLK) scatter_body(b, srcv, dstv, hscan, sorted, E, chunk, nbuck);
    else gemm_f32_body(b - NBLK, A, whi, wlo, C, Nrows);
}

// ---------------- scan phase 1: per-block inclusive scan ----------------
__global__ __launch_bounds__(SCAN_B) void scan1_kernel(const int* __restrict__ in,
                                                       int* __restrict__ out,
                                                       int* __restrict__ sums, int n) {
    __shared__ int s[SCAN_B];
    int t = threadIdx.x;
    int idx = blockIdx.x * SCAN_B + t;
    int v = (idx < n) ? in[idx] : 0;
    s[t] = v;
    __syncthreads();
    for (int off = 1; off < SCAN_B; off <<= 1) {
        int x = (t >= off) ? s[t - off] : 0;
        __syncthreads();
        s[t] += x;
        __syncthreads();
    }
    if (idx < n) out[idx] = s[t];
    if (t == SCAN_B - 1) sums[blockIdx.x] = s[t];
}

// ---------------- scan phase 2+3 fused; block 0 also zeroes the dummy row ----------------
__global__ __launch_bounds__(SCAN_B) void scan3_kernel(const int* __restrict__ in,
                                                       int* __restrict__ inout,
                                                       const int* __restrict__ sums,
                                                       int n,
                                                       unsigned short* __restrict__ m,
                                                       unsigned short* __restrict__ m2,
                                                       float* __restrict__ dinv, int N) {
    __shared__ int s[SCAN_B];
    int t = threadIdx.x;
    int b = blockIdx.x;                 // gridDim.x <= 256 required
    s[t] = (t < b) ? sums[t] : 0;
    __syncthreads();
    for (int off = SCAN_B / 2; off > 0; off >>= 1) {
        if (t < off) s[t] += s[t + off];
        __syncthreads();
    }
    int base = s[0];
    int idx = b * SCAN_B + t;
    if (idx < n) inout[idx] = inout[idx] - in[idx] + base;
    // dummy node N: zero row in m and m2, dinv[N]=0  (gather padding adds exact +0)
    if (b == 0) {
        unsigned* mr = (unsigned*)(m + (size_t)N * HDIM);
        unsigned* m2r = (unsigned*)(m2 + (size_t)N * HDIM);
        if (t < 64) mr[t] = 0u;
        else if (t < 128) m2r[t - 64] = 0u;
        else if (t == 128) dinv[N] = 0.f;
    }
}

// ---------------- Pass D: per-bucket PADDED CSR build ----------------
// Each node's row is padded to a multiple of 8 with dummy index N (zero row,
// dinv 0) -> gather loops are tail-free and rowstart is 8-aligned (int4 idx loads).
// Per-node padded length goes to rowlen[]; inter-bucket gaps are never read.
__global__ __launch_bounds__(256) void csr_kernel(const int2* __restrict__ sorted,
                                                  const int* __restrict__ hscan,
                                                  int* __restrict__ rowstart,
                                                  int* __restrict__ rowlen,
                                                  float* __restrict__ dinv,
                                                  int* __restrict__ csr,
                                                  int N, int E, int nbuck) {
    __shared__ int cnt[256];
    __shared__ int s[256];
    __shared__ int cur[256];
    int b = blockIdx.x;
    int t = threadIdx.x;
    int start = hscan[b * NBLK];
    int end = (b + 1 < nbuck) ? hscan[(b + 1) * NBLK] : E;
    cnt[t] = 0;
    __syncthreads();
    for (int e = start + t; e < end; e += 256)
        atomicAdd(&cnt[sorted[e].y & 255], 1);
    __syncthreads();
    int v = cnt[t];
    int pc = (v + 7) & ~7;              // padded count (multiple of 8)
    s[t] = pc;
    __syncthreads();
    for (int off = 1; off < 256; off <<= 1) {
        int x = (t >= off) ? s[t - off] : 0;
        __syncthreads();
        s[t] += x;
        __syncthreads();
    }
    int pexcl = s[t] - pc;
    int pbase = ((start + 7) & ~7) + b * BPAD;   // 8-aligned; capacity >= real+1793
    int node = b * 256 + t;
    if (node < N) {
        rowstart[node] = pbase + pexcl;
        rowlen[node] = pc;
        dinv[node] = rsqrtf((float)(v + 1));   // +1 self-loop (real degree)
    }
    cur[t] = pbase + pexcl;
    __syncthreads();
    for (int e = start + t; e < end; e += 256) {
        int2 ed = sorted[e];
        int pos = atomicAdd(&cur[ed.y & 255], 1);
        csr[pos] = ed.x;
    }
    // pad own node's slots with dummy index N (no sync needed: slots are private)
    if (node < N) {
        int base2 = pbase + pexcl;
        for (int j = v; j < pc; ++j) csr[base2 + j] = N;
    }
}

// ---------------- gather primitives ----------------
// WEIGHTED: acc += dinv[s] * m[s]  (layer-1 rows unscaled)
// !WEIGHTED: acc += m[s]           (layer-2 rows pre-scaled by dinv[src])
template <bool W>
__device__ inline void qacc1(float* acc, uint4 uv, float wt) {
    if (W) {
        acc[0] = fmaf(wt, bf_lo(uv.x), acc[0]);
        acc[1] = fmaf(wt, bf_hi(uv.x), acc[1]);
        acc[2] = fmaf(wt, bf_lo(uv.y), acc[2]);
        acc[3] = fmaf(wt, bf_hi(uv.y), acc[3]);
        acc[4] = fmaf(wt, bf_lo(uv.z), acc[4]);
        acc[5] = fmaf(wt, bf_hi(uv.z), acc[5]);
        acc[6] = fmaf(wt, bf_lo(uv.w), acc[6]);
        acc[7] = fmaf(wt, bf_hi(uv.w), acc[7]);
    } else {
        acc[0] += bf_lo(uv.x); acc[1] += bf_hi(uv.x);
        acc[2] += bf_lo(uv.y); acc[3] += bf_hi(uv.y);
        acc[4] += bf_lo(uv.z); acc[5] += bf_hi(uv.z);
        acc[6] += bf_lo(uv.w); acc[7] += bf_hi(uv.w);
    }
}

// Tail-free gather: row lengths are multiples of 8, rowstart 8-aligned.
// Per batch: 2 int4 index loads + (8 dinv) + 8 row loads, then adds.
template <bool W>
__device__ inline void qgather(const uint4* __restrict__ m4,
                               const int* __restrict__ csr,
                               const float* __restrict__ dinv,
                               int p, int pend, int t, float* acc) {
    for (; p < pend; p += 8) {
        int4 i0 = *(const int4*)&csr[p];
        int4 i1 = *(const int4*)&csr[p + 4];
        uint4 u0 = m4[(size_t)i0.x * 16 + t];
        uint4 u1 = m4[(size_t)i0.y * 16 + t];
        uint4 u2 = m4[(size_t)i0.z * 16 + t];
        uint4 u3 = m4[(size_t)i0.w * 16 + t];
        uint4 u4 = m4[(size_t)i1.x * 16 + t];
        uint4 u5 = m4[(size_t)i1.y * 16 + t];
        uint4 u6 = m4[(size_t)i1.z * 16 + t];
        uint4 u7 = m4[(size_t)i1.w * 16 + t];
        float w0 = 0.f, w1 = 0.f, w2 = 0.f, w3 = 0.f;
        float w4 = 0.f, w5 = 0.f, w6 = 0.f, w7 = 0.f;
        if (W) {
            w0 = dinv[i0.x]; w1 = dinv[i0.y]; w2 = dinv[i0.z]; w3 = dinv[i0.w];
            w4 = dinv[i1.x]; w5 = dinv[i1.y]; w6 = dinv[i1.z]; w7 = dinv[i1.w];
        }
        qacc1<W>(acc, u0, w0); qacc1<W>(acc, u1, w1);
        qacc1<W>(acc, u2, w2); qacc1<W>(acc, u3, w3);
        qacc1<W>(acc, u4, w4); qacc1<W>(acc, u5, w5);
        qacc1<W>(acc, u6, w6); qacc1<W>(acc, u7, w7);
    }
}

// In-block degree sort: rank the block's 16 nodes by (padded) row length desc so
// each wave's 4 quarter-nodes have similar trip counts. Stashes starts/lengths.
__device__ inline int degree_perm(const int* __restrict__ rowstart,
                                  const int* __restrict__ rowlen,
                                  int* lens, int* rs, int* perm, int n) {
    if (threadIdx.x < 16) {
        int nn = blockIdx.x * 16 + threadIdx.x;
        rs[threadIdx.x] = (nn < n) ? rowstart[nn] : 0;
        lens[threadIdx.x] = (nn < n) ? rowlen[nn] : -1;
    }
    __syncthreads();
    if (threadIdx.x < 16) {
        int L = lens[threadIdx.x];
        int r = 0;
#pragma unroll
        for (int j = 0; j < 16; ++j) {
            int Lj = lens[j];
            r += (Lj > L || (Lj == L && j < (int)threadIdx.x)) ? 1 : 0;
        }
        perm[r] = threadIdx.x;
    }
    __syncthreads();
    return perm[threadIdx.x >> 4];
}

// ---------------- fused agg(layer1) + gemm(layer2): m2 = dinv*bf16(relu(agg)+b1)@W2 ----------------
__global__ __launch_bounds__(256) void agg_gemm_kernel(
        const uint4* __restrict__ m4,
        const int* __restrict__ rowstart,
        const int* __restrict__ rowlen,
        const int* __restrict__ csr,
        const float* __restrict__ dinv,
        const float* __restrict__ bias,
        const unsigned short* __restrict__ whi,   // W2 frags
        const unsigned short* __restrict__ wlo,
        uint4* __restrict__ out_m, int n) {
    __shared__ unsigned short hbuf[16][HDIM + 8];   // bf16 h tile (+16B pad)
    __shared__ float cbuf[16][HDIM + 4];            // fp32 C tile (+16B pad)
    __shared__ int lens[16];
    __shared__ int rs[16];
    __shared__ int perm[16];
    int t = threadIdx.x & 15;

    int pnl = degree_perm(rowstart, rowlen, lens, rs, perm, n);
    int node = blockIdx.x * 16 + pnl;

    // ---- agg phase (processes node `pnl`, writes hbuf[pnl]) ----
    unsigned short hv[8] = {0, 0, 0, 0, 0, 0, 0, 0};
    if (node < n) {
        float dd = dinv[node];
        float acc[8];
        uint4 u = m4[(size_t)node * 16 + t];
        acc[0] = dd * bf_lo(u.x); acc[1] = dd * bf_hi(u.x);
        acc[2] = dd * bf_lo(u.y); acc[3] = dd * bf_hi(u.y);
        acc[4] = dd * bf_lo(u.z); acc[5] = dd * bf_hi(u.z);
        acc[6] = dd * bf_lo(u.w); acc[7] = dd * bf_hi(u.w);
        int p0 = rs[pnl];
        qgather<true>(m4, csr, dinv, p0, p0 + lens[pnl], t, acc);
        float4 b0 = *(const float4*)&bias[t * 8];
        float4 b1 = *(const float4*)&bias[t * 8 + 4];
        float bb[8] = {b0.x, b0.y, b0.z, b0.w, b1.x, b1.y, b1.z, b1.w};
#pragma unroll
        for (int j = 0; j < 8; ++j)
            hv[j] = f2bf_rne(fmaxf(fmaf(dd, acc[j], bb[j]), 0.f));
    }
    *(uint4*)&hbuf[pnl][t * 8] = *(uint4*)hv;
    __syncthreads();

    // ---- gemm phase: each wave does 2 column tiles, all 4 kt ----
    int w = threadIdx.x >> 6, L = threadIdx.x & 63;
    int lm = L & 15, lq = L >> 4;
    f32x4 acc2[2];
    acc2[0] = (f32x4)(0.f);
    acc2[1] = (f32x4)(0.f);
#pragma unroll
    for (int kt = 0; kt < 4; ++kt) {
        bfrag a = *(const bfrag*)&hbuf[lm][kt * 32 + lq * 8];
#pragma unroll
        for (int q2 = 0; q2 < 2; ++q2) {
            int nt = w * 2 + q2;
            int o = ((kt * 8 + nt) * 64 + L) * 8;
            bfrag wh = *(const bfrag*)&whi[o];
            bfrag wl = *(const bfrag*)&wlo[o];
            acc2[q2] = __builtin_amdgcn_mfma_f32_16x16x32_bf16(a, wh, acc2[q2], 0, 0, 0);
            acc2[q2] = __builtin_amdgcn_mfma_f32_16x16x32_bf16(a, wl, acc2[q2], 0, 0, 0);
        }
    }
    // C/D layout: col(in tile)=lane&15, row=(lane>>4)*4+i; logical col = lm*8+nt
#pragma unroll
    for (int q2 = 0; q2 < 2; ++q2) {
        int nt = w * 2 + q2;
#pragma unroll
        for (int i = 0; i < 4; ++i) cbuf[lq * 4 + i][lm * 8 + nt] = acc2[q2][i];
    }
    __syncthreads();

    // ---- repack + pre-scale by dinv + round + store (original node order) ----
    int nl = threadIdx.x >> 4;
    int node_e = blockIdx.x * 16 + nl;
    if (node_e < n) {
        float dde = dinv[node_e];
        float4 r0 = *(const float4*)&cbuf[nl][t * 8];
        float4 r1 = *(const float4*)&cbuf[nl][t * 8 + 4];
        unsigned short ev[8];
        ev[0] = f2bf_rne(dde * r0.x); ev[1] = f2bf_rne(dde * r0.y);
        ev[2] = f2bf_rne(dde * r0.z); ev[3] = f2bf_rne(dde * r0.w);
        ev[4] = f2bf_rne(dde * r1.x); ev[5] = f2bf_rne(dde * r1.y);
        ev[6] = f2bf_rne(dde * r1.z); ev[7] = f2bf_rne(dde * r1.w);
        out_m[(size_t)node_e * 16 + t] = *(uint4*)ev;
    }
}

// ---------------- agg layer 2 fused with global max pool ----------------
// m2 rows pre-scaled by dinv[src] -> pure-add gather; degree-sorted waves.
__global__ __launch_bounds__(256) void agg_pool_kernel(const uint4* __restrict__ m4,
                                                       const int* __restrict__ rowstart,
                                                       const int* __restrict__ rowlen,
                                                       const int* __restrict__ csr,
                                                       const float* __restrict__ dinv,
                                                       const float* __restrict__ bias,
                                                       const int* __restrict__ batch,
                                                       unsigned int* __restrict__ g, int n) {
    __shared__ float smx[16][HDIM];
    __shared__ int sgid[16];
    __shared__ int lens[16];
    __shared__ int rs[16];
    __shared__ int perm[16];
    int t = threadIdx.x & 15;

    int pnl = degree_perm(rowstart, rowlen, lens, rs, perm, n);
    int node = blockIdx.x * 16 + pnl;
    bool valid = node < n;
    if (valid) {
        float dd = dinv[node];
        float acc[8];
        uint4 u = m4[(size_t)node * 16 + t];
        acc[0] = bf_lo(u.x); acc[1] = bf_hi(u.x);
        acc[2] = bf_lo(u.y); acc[3] = bf_hi(u.y);
        acc[4] = bf_lo(u.z); acc[5] = bf_hi(u.z);
        acc[6] = bf_lo(u.w); acc[7] = bf_hi(u.w);
        int p0 = rs[pnl];
        qgather<false>(m4, csr, dinv, p0, p0 + lens[pnl], t, acc);
        float4 b0 = *(const float4*)&bias[t * 8];
        float4 b1 = *(const float4*)&bias[t * 8 + 4];
        float4 r0, r1;
        r0.x = fmaxf(fmaf(dd, acc[0], b0.x), 0.f);
        r0.y = fmaxf(fmaf(dd, acc[1], b0.y), 0.f);
        r0.z = fmaxf(fmaf(dd, acc[2], b0.z), 0.f);
        r0.w = fmaxf(fmaf(dd, acc[3], b0.w), 0.f);
        r1.x = fmaxf(fmaf(dd, acc[4], b1.x), 0.f);
        r1.y = fmaxf(fmaf(dd, acc[5], b1.y), 0.f);
        r1.z = fmaxf(fmaf(dd, acc[6], b1.z), 0.f);
        r1.w = fmaxf(fmaf(dd, acc[7], b1.w), 0.f);
        *(float4*)&smx[pnl][t * 8] = r0;
        *(float4*)&smx[pnl][t * 8 + 4] = r1;
    }
    if (t == 0) sgid[pnl] = valid ? batch[node] : -1;
    __syncthreads();
    // smx/sgid indexed by original node order -> batch runs stay contiguous.
    if (threadIdx.x < HDIM) {
        int c = threadIdx.x;
        int curg = -1;
        float run = 0.f;
#pragma unroll
        for (int r = 0; r < 16; ++r) {
            int gg = sgid[r];
            if (gg < 0) continue;
            if (gg != curg) {
                if (curg >= 0) atomicMax(&g[curg * HDIM + c], __float_as_uint(run));
                curg = gg;
                run = smx[r][c];
            } else {
                run = fmaxf(run, smx[r][c]);
            }
        }
        if (curg >= 0) atomicMax(&g[curg * HDIM + c], __float_as_uint(run));
    }
}

// ---------------- MLP head + log_softmax ----------------
__global__ __launch_bounds__(128) void mlp_kernel(const unsigned int* __restrict__ gbits,
                                                  const float* __restrict__ W3,
                                                  const float* __restrict__ b3,
                                                  const float* __restrict__ W4,
                                                  const float* __restrict__ b4,
                                                  float* __restrict__ out) {
    __shared__ float gs[HDIM];
    __shared__ float r0[HDIM];
    __shared__ float r1[HDIM];
    int j = threadIdx.x;
    int b = blockIdx.x;
    gs[j] = __uint_as_float(gbits[b * HDIM + j]);
    __syncthreads();
    float acc = b3[j];
#pragma unroll 8
    for (int k = 0; k < HDIM; ++k) acc = fmaf(gs[k], W3[k * HDIM + j], acc);
    float z = fmaxf(acc, 0.f);
    r0[j] = z * W4[j * 2 + 0];
    r1[j] = z * W4[j * 2 + 1];
    __syncthreads();
    for (int off = 64; off > 0; off >>= 1) {
        if (j < off) {
            r0[j] += r0[j + off];
            r1[j] += r1[j + off];
        }
        __syncthreads();
    }
    if (j == 0) {
        float l0 = r0[0] + b4[0];
        float l1 = r1[0] + b4[1];
        float mx = fmaxf(l0, l1);
        float lse = mx + logf(expf(l0 - mx) + expf(l1 - mx));
        out[b * 2 + 0] = l0 - lse;
        out[b * 2 + 1] = l1 - lse;
    }
}

extern "C" void kernel_launch(void* const* d_in, const int* in_sizes, int n_in,
                              void* d_out, int out_size, void* d_ws, size_t ws_size,
                              hipStream_t stream) {
    const float* x  = (const float*)d_in[0];
    const float* W1 = (const float*)d_in[1];
    const float* b1 = (const float*)d_in[2];
    const float* W2 = (const float*)d_in[3];
    const float* b2 = (const float*)d_in[4];
    const float* W3 = (const float*)d_in[5];
    const float* b3 = (const float*)d_in[6];
    const float* W4 = (const float*)d_in[7];
    const float* b4 = (const float*)d_in[8];
    const int* ei    = (const int*)d_in[9];
    const int* batch = (const int*)d_in[10];

    const int N = in_sizes[0] / HDIM;   // 50000
    const int E = in_sizes[9] / 2;      // 640000
    const int G = out_size / 2;         // 64
    const int* src = ei;
    const int* dst = ei + E;

    const int nbuck = (N + 255) >> 8;        // 196 (must be <= 256)
    const int nscan = nbuck * NBLK;          // 50176
    const int chunk = (E + NBLK - 1) / NBLK; // 2500

    // ---- workspace layout (16B-aligned blocks) ----
    const int Nr = ((N + 63) / 64) * 64;
    char* wsb = (char*)d_ws;
    size_t o = 0;
    unsigned int* g = (unsigned int*)(wsb + o); o += (size_t)G * HDIM * 4;
    size_t zero_bytes = o;                 // only g needs zeroing
    int* hist = (int*)(wsb + o);           o += (size_t)nscan * 4;
    int* hscan = (int*)(wsb + o);          o += (size_t)nscan * 4;
    int* sums = (int*)(wsb + o);           o += 256 * 4;
    int* rowstart = (int*)(wsb + o);       o += (size_t)(Nr + 64) * 4;
    int* rowlen = (int*)(wsb + o);         o += (size_t)(Nr + 64) * 4;
    float* dinv = (float*)(wsb + o);       o += (size_t)Nr * 4;
    int2* sorted = (int2*)(wsb + o);       o += (size_t)E * 8;
    int* csr = (int*)(wsb + o);            o += ((size_t)E + (size_t)nbuck * BPAD + 2048) * 4;
    unsigned short* wf1h = (unsigned short*)(wsb + o); o += (size_t)HDIM * HDIM * 2;
    unsigned short* wf1l = (unsigned short*)(wsb + o); o += (size_t)HDIM * HDIM * 2;
    unsigned short* wf2h = (unsigned short*)(wsb + o); o += (size_t)HDIM * HDIM * 2;
    unsigned short* wf2l = (unsigned short*)(wsb + o); o += (size_t)HDIM * HDIM * 2;
    unsigned short* m = (unsigned short*)(wsb + o);    o += (size_t)(Nr + 64) * HDIM * 2;
    unsigned short* m2 = (unsigned short*)(wsb + o);   o += (size_t)(Nr + 64) * HDIM * 2;
    (void)ws_size; (void)n_in;

    (void)hipMemsetAsync(d_ws, 0, zero_bytes, stream);

    int sblocks = (nscan + SCAN_B - 1) / SCAN_B;   // 196 (<= 256 required)
    int gemm_blocks = (N + GBM - 1) / GBM;         // 782
    int agg_blocks = (N + 15) / 16;                // 3125

    // K1: hist || wfrag  (independent)
    mega1_kernel<<<NBLK + 128, 256, 0, stream>>>(dst, hist, E, chunk, nbuck,
                                                 W1, W2, wf1h, wf1l, wf2h, wf2l);
    // K2: scan of hist matrix (bucket-major) -> hscan exclusive (2 dispatches);
    //     scan3 block 0 also zeroes dummy row N of m/m2 and dinv[N]
    scan1_kernel<<<sblocks, SCAN_B, 0, stream>>>(hist, hscan, sums, nscan);
    scan3_kernel<<<sblocks, SCAN_B, 0, stream>>>(hist, hscan, sums, nscan, m, m2, dinv, N);
    // K3: scatter (bucket sort) || gemm layer 1
    mega3_kernel<<<NBLK + gemm_blocks, 256, 0, stream>>>(src, dst, hscan, sorted,
                                                         E, chunk, nbuck,
                                                         x, wf1h, wf1l, m, N);
    // K4: per-bucket PADDED CSR build (rowstart, rowlen, dinv, csr)
    csr_kernel<<<nbuck, 256, 0, stream>>>(sorted, hscan, rowstart, rowlen, dinv, csr,
                                          N, E, nbuck);
    // K5: fused agg(layer1) + gemm(layer2) -> m2 (dinv-pre-scaled)
    agg_gemm_kernel<<<agg_blocks, 256, 0, stream>>>((const uint4*)m, rowstart, rowlen,
                                                    csr, dinv, b1, wf2h, wf2l,
                                                    (uint4*)m2, N);
    // K6: agg layer 2 + global max pool
    agg_pool_kernel<<<agg_blocks, 256, 0, stream>>>((const uint4*)m2, rowstart, rowlen,
                                                    csr, dinv, b2, batch, g, N);
    // K7: MLP head + log_softmax
    mlp_kernel<<<G, 128, 0, stream>>>(g, W3, b3, W4, b4, (float*)d_out);
}

// Round 9
// 195.916 us; speedup vs baseline: 1.1047x; 1.0084x over previous
//
#include <hip/hip_runtime.h>
#include <hip/hip_bf16.h>
#include <math.h>

// ---------------- constants ----------------
#define HDIM 128
#define SCAN_B 256
#define NBLK 256          // edge blocks for hist/scatter passes
#define BPAD 1800         // per-bucket extra CSR capacity for padding (multiple of 8)

typedef short bfrag __attribute__((ext_vector_type(8)));   // 8 bf16 (4 VGPRs)
typedef float f32x4 __attribute__((ext_vector_type(4)));   // 4 fp32 acc

__device__ inline unsigned short f2bf_rne(float x) {
    unsigned u = __float_as_uint(x);
    u = (u + 0x7fffu + ((u >> 16) & 1u)) >> 16;
    return (unsigned short)u;
}
__device__ inline float bf_lo(unsigned u) { return __uint_as_float(u << 16); }
__device__ inline float bf_hi(unsigned u) { return __uint_as_float(u & 0xffff0000u); }

// ---------------- device bodies ----------------

// Pass A: per-block LDS coarse histogram (dst>>8); no global atomics.
__device__ inline void hist_body(int b, const int* __restrict__ dst,
                                 int* __restrict__ hist, int E, int chunk, int nbuck) {
    __shared__ int hl[256];
    int t = threadIdx.x;
    hl[t] = 0;
    __syncthreads();
    int start = b * chunk, end = min(E, start + chunk);
    for (int e = start + t; e < end; e += 256) atomicAdd(&hl[dst[e] >> 8], 1);
    __syncthreads();
    if (t < nbuck) hist[t * NBLK + b] = hl[t];
}

// W -> fragment-ordered bf16 hi/lo, column-permuted: physical slot (nt, lm)
// carries logical column n_l = lm*8 + nt (so epilogue stores are 16B packed).
__device__ inline void wfrag_body(int b, const float* __restrict__ W1,
                                  const float* __restrict__ W2,
                                  unsigned short* __restrict__ w1h,
                                  unsigned short* __restrict__ w1l,
                                  unsigned short* __restrict__ w2h,
                                  unsigned short* __restrict__ w2l) {
    const float* W = (b < 64) ? W1 : W2;
    unsigned short* whi = (b < 64) ? w1h : w2h;
    unsigned short* wlo = (b < 64) ? w1l : w2l;
    int idx = (b & 63) * 256 + threadIdx.x;     // 0..16383
    int k = idx >> 7;
    int n = idx & 127;
    int kt = k >> 5, q = (k >> 3) & 3, j = k & 7;
    int lm = n >> 3, nt = n & 7;
    int lane = q * 16 + lm;
    int o = ((kt * 8 + nt) * 64 + lane) * 8 + j;
    float x = W[idx];
    unsigned short hb = f2bf_rne(x);
    float hf = __uint_as_float(((unsigned)hb) << 16);
    unsigned short lb = f2bf_rne(x - hf);
    whi[o] = hb;
    wlo[o] = lb;
}

// Pass C: scatter edges into bucket-sorted order via LDS cursors (no global atomics).
__device__ inline void scatter_body(int b, const int* __restrict__ srcv,
                                    const int* __restrict__ dstv,
                                    const int* __restrict__ hscan,
                                    int2* __restrict__ sorted,
                                    int E, int chunk, int nbuck) {
    __shared__ int cur[256];
    int t = threadIdx.x;
    if (t < nbuck) cur[t] = hscan[t * NBLK + b];
    __syncthreads();
    int start = b * chunk, end = min(E, start + chunk);
    for (int e = start + t; e < end; e += 256) {
        int d = dstv[e];
        int pos = atomicAdd(&cur[d >> 8], 1);
        sorted[pos] = make_int2(srcv[e], d);
    }
}

// MFMA GEMM (fp32 A), 64-row tiles, split 3-MFMA: C ~= Ah*Wh + Al*Wh + Ah*Wl
#define GBM 64
__device__ inline void gemm_f32_body(int b, const float* __restrict__ A,
                                     const unsigned short* __restrict__ whi,
                                     const unsigned short* __restrict__ wlo,
                                     unsigned short* __restrict__ C, int Nrows) {
    int tid = threadIdx.x;
    int w = tid >> 6, L = tid & 63;
    int lm = L & 15, lq = L >> 4;
    int row0 = b * GBM + w * 16;

    f32x4 acc[8];
#pragma unroll
    for (int nt = 0; nt < 8; ++nt) acc[nt] = (f32x4)(0.f);

#pragma unroll
    for (int kt = 0; kt < 4; ++kt) {
        int gr = row0 + lm;
        float4 v0 = make_float4(0.f, 0.f, 0.f, 0.f);
        float4 v1 = v0;
        if (gr < Nrows) {
            const float* p = &A[(size_t)gr * HDIM + kt * 32 + lq * 8];
            v0 = *(const float4*)p;
            v1 = *(const float4*)(p + 4);
        }
        float xv[8] = {v0.x, v0.y, v0.z, v0.w, v1.x, v1.y, v1.z, v1.w};
        bfrag ah, al;
#pragma unroll
        for (int j = 0; j < 8; ++j) {
            float x = xv[j];
            unsigned short hb = f2bf_rne(x);
            float hf = __uint_as_float(((unsigned)hb) << 16);
            unsigned short lb = f2bf_rne(x - hf);
            ah[j] = (short)hb;
            al[j] = (short)lb;
        }
#pragma unroll
        for (int nt = 0; nt < 8; ++nt) {
            int o = ((kt * 8 + nt) * 64 + L) * 8;
            bfrag wh = *(const bfrag*)&whi[o];
            bfrag wl = *(const bfrag*)&wlo[o];
            acc[nt] = __builtin_amdgcn_mfma_f32_16x16x32_bf16(ah, wh, acc[nt], 0, 0, 0);
            acc[nt] = __builtin_amdgcn_mfma_f32_16x16x32_bf16(al, wh, acc[nt], 0, 0, 0);
            acc[nt] = __builtin_amdgcn_mfma_f32_16x16x32_bf16(ah, wl, acc[nt], 0, 0, 0);
        }
    }

#pragma unroll
    for (int i = 0; i < 4; ++i) {
        int gr = row0 + lq * 4 + i;
        if (gr < Nrows) {
            bfrag e;
#pragma unroll
            for (int nt = 0; nt < 8; ++nt) e[nt] = (short)f2bf_rne(acc[nt][i]);
            *(bfrag*)&C[(size_t)gr * HDIM + lm * 8] = e;
        }
    }
}

// ---------------- megakernel 1: hist || wfrag ----------------
__global__ __launch_bounds__(256) void mega1_kernel(const int* __restrict__ dst,
                                                    int* __restrict__ hist, int E,
                                                    int chunk, int nbuck,
                                                    const float* __restrict__ W1,
                                                    const float* __restrict__ W2,
                                                    unsigned short* __restrict__ w1h,
                                                    unsigned short* __restrict__ w1l,
                                                    unsigned short* __restrict__ w2h,
                                                    unsigned short* __restrict__ w2l) {
    int b = blockIdx.x;
    if (b < NBLK) hist_body(b, dst, hist, E, chunk, nbuck);
    else wfrag_body(b - NBLK, W1, W2, w1h, w1l, w2h, w2l);
}

// ---------------- megakernel 3: scatter || gemm_f32(layer1) ----------------
__global__ __launch_bounds__(256) void mega3_kernel(const int* __restrict__ srcv,
                                                    const int* __restrict__ dstv,
                                                    const int* __restrict__ hscan,
                                                    int2* __restrict__ sorted,
                                                    int E, int chunk, int nbuck,
                                                    const float* __restrict__ A,
                                                    const unsigned short* __restrict__ whi,
                                                    const unsigned short* __restrict__ wlo,
                                                    unsigned short* __restrict__ C, int Nrows) {
    int b = blockIdx.x;
    if (b < NBLK) scatter_body(b, srcv, dstv, hscan, sorted, E, chunk, nbuck);
    else gemm_f32_body(b - NBLK, A, whi, wlo, C, Nrows);
}

// ---------------- scan phase 1: per-block inclusive scan ----------------
__global__ __launch_bounds__(SCAN_B) void scan1_kernel(const int* __restrict__ in,
                                                       int* __restrict__ out,
                                                       int* __restrict__ sums, int n) {
    __shared__ int s[SCAN_B];
    int t = threadIdx.x;
    int idx = blockIdx.x * SCAN_B + t;
    int v = (idx < n) ? in[idx] : 0;
    s[t] = v;
    __syncthreads();
    for (int off = 1; off < SCAN_B; off <<= 1) {
        int x = (t >= off) ? s[t - off] : 0;
        __syncthreads();
        s[t] += x;
        __syncthreads();
    }
    if (idx < n) out[idx] = s[t];
    if (t == SCAN_B - 1) sums[blockIdx.x] = s[t];
}

// ---------------- scan phase 2+3 fused; block 0 also zeroes the dummy row ----------------
__global__ __launch_bounds__(SCAN_B) void scan3_kernel(const int* __restrict__ in,
                                                       int* __restrict__ inout,
                                                       const int* __restrict__ sums,
                                                       int n,
                                                       unsigned short* __restrict__ m,
                                                       unsigned short* __restrict__ m2,
                                                       float* __restrict__ dinv, int N) {
    __shared__ int s[SCAN_B];
    int t = threadIdx.x;
    int b = blockIdx.x;                 // gridDim.x <= 256 required
    s[t] = (t < b) ? sums[t] : 0;
    __syncthreads();
    for (int off = SCAN_B / 2; off > 0; off >>= 1) {
        if (t < off) s[t] += s[t + off];
        __syncthreads();
    }
    int base = s[0];
    int idx = b * SCAN_B + t;
    if (idx < n) inout[idx] = inout[idx] - in[idx] + base;
    // dummy node N: zero row in m and m2, dinv[N]=0  (gather padding adds exact +0)
    if (b == 0) {
        unsigned* mr = (unsigned*)(m + (size_t)N * HDIM);
        unsigned* m2r = (unsigned*)(m2 + (size_t)N * HDIM);
        if (t < 64) mr[t] = 0u;
        else if (t < 128) m2r[t - 64] = 0u;
        else if (t == 128) dinv[N] = 0.f;
    }
}

// ---------------- Pass D: per-bucket PADDED CSR build ----------------
// Each node's row is padded to a multiple of 8 with dummy index N (zero row,
// dinv 0) -> gather loops are tail-free and rowstart is 8-aligned (int4 idx loads).
// Per-node padded length goes to rowlen[]; inter-bucket gaps are never read.
__global__ __launch_bounds__(256) void csr_kernel(const int2* __restrict__ sorted,
                                                  const int* __restrict__ hscan,
                                                  int* __restrict__ rowstart,
                                                  int* __restrict__ rowlen,
                                                  float* __restrict__ dinv,
                                                  int* __restrict__ csr,
                                                  int N, int E, int nbuck) {
    __shared__ int cnt[256];
    __shared__ int s[256];
    __shared__ int cur[256];
    int b = blockIdx.x;
    int t = threadIdx.x;
    int start = hscan[b * NBLK];
    int end = (b + 1 < nbuck) ? hscan[(b + 1) * NBLK] : E;
    cnt[t] = 0;
    __syncthreads();
    for (int e = start + t; e < end; e += 256)
        atomicAdd(&cnt[sorted[e].y & 255], 1);
    __syncthreads();
    int v = cnt[t];
    int pc = (v + 7) & ~7;              // padded count (multiple of 8)
    s[t] = pc;
    __syncthreads();
    for (int off = 1; off < 256; off <<= 1) {
        int x = (t >= off) ? s[t - off] : 0;
        __syncthreads();
        s[t] += x;
        __syncthreads();
    }
    int pexcl = s[t] - pc;
    int pbase = ((start + 7) & ~7) + b * BPAD;   // 8-aligned; capacity >= real+1793
    int node = b * 256 + t;
    if (node < N) {
        rowstart[node] = pbase + pexcl;
        rowlen[node] = pc;
        dinv[node] = rsqrtf((float)(v + 1));   // +1 self-loop (real degree)
    }
    cur[t] = pbase + pexcl;
    __syncthreads();
    for (int e = start + t; e < end; e += 256) {
        int2 ed = sorted[e];
        int pos = atomicAdd(&cur[ed.y & 255], 1);
        csr[pos] = ed.x;
    }
    // pad own node's slots with dummy index N (no sync needed: slots are private)
    if (node < N) {
        int base2 = pbase + pexcl;
        for (int j = v; j < pc; ++j) csr[base2 + j] = N;
    }
}

// ---------------- gather primitives ----------------
// WEIGHTED: acc += dinv[s] * m[s]  (layer-1 rows unscaled)
// !WEIGHTED: acc += m[s]           (layer-2 rows pre-scaled by dinv[src])
template <bool W>
__device__ inline void qacc1(float* acc, uint4 uv, float wt) {
    if (W) {
        acc[0] = fmaf(wt, bf_lo(uv.x), acc[0]);
        acc[1] = fmaf(wt, bf_hi(uv.x), acc[1]);
        acc[2] = fmaf(wt, bf_lo(uv.y), acc[2]);
        acc[3] = fmaf(wt, bf_hi(uv.y), acc[3]);
        acc[4] = fmaf(wt, bf_lo(uv.z), acc[4]);
        acc[5] = fmaf(wt, bf_hi(uv.z), acc[5]);
        acc[6] = fmaf(wt, bf_lo(uv.w), acc[6]);
        acc[7] = fmaf(wt, bf_hi(uv.w), acc[7]);
    } else {
        acc[0] += bf_lo(uv.x); acc[1] += bf_hi(uv.x);
        acc[2] += bf_lo(uv.y); acc[3] += bf_hi(uv.y);
        acc[4] += bf_lo(uv.z); acc[5] += bf_hi(uv.z);
        acc[6] += bf_lo(uv.w); acc[7] += bf_hi(uv.w);
    }
}

// Tail-free, ROW-PIPELINED gather: row lengths are multiples of 8, rowstart
// 8-aligned. Batch k+1's index+row+weight loads are issued BEFORE batch k's
// adds, so the adds' waitcnt leaves the next batch's 8 row loads in flight
// (counted vmcnt within the loop body -> in-flight never drains to 0).
// Accumulation order is identical to the non-pipelined loop (bit-exact).
template <bool W>
__device__ inline void qgather(const uint4* __restrict__ m4,
                               const int* __restrict__ csr,
                               const float* __restrict__ dinv,
                               int p, int pend, int t, float* acc) {
    if (p >= pend) return;
    int4 ia = *(const int4*)&csr[p];
    int4 ib = *(const int4*)&csr[p + 4];
    uint4 u0 = m4[(size_t)ia.x * 16 + t];
    uint4 u1 = m4[(size_t)ia.y * 16 + t];
    uint4 u2 = m4[(size_t)ia.z * 16 + t];
    uint4 u3 = m4[(size_t)ia.w * 16 + t];
    uint4 u4 = m4[(size_t)ib.x * 16 + t];
    uint4 u5 = m4[(size_t)ib.y * 16 + t];
    uint4 u6 = m4[(size_t)ib.z * 16 + t];
    uint4 u7 = m4[(size_t)ib.w * 16 + t];
    float w0 = 0.f, w1 = 0.f, w2 = 0.f, w3 = 0.f;
    float w4 = 0.f, w5 = 0.f, w6 = 0.f, w7 = 0.f;
    if (W) {
        w0 = dinv[ia.x]; w1 = dinv[ia.y]; w2 = dinv[ia.z]; w3 = dinv[ia.w];
        w4 = dinv[ib.x]; w5 = dinv[ib.y]; w6 = dinv[ib.z]; w7 = dinv[ib.w];
    }
    for (p += 8; p < pend; p += 8) {
        // ---- issue batch k+1 (indices, rows, weights) ----
        int4 ja = *(const int4*)&csr[p];
        int4 jb = *(const int4*)&csr[p + 4];
        uint4 v0 = m4[(size_t)ja.x * 16 + t];
        uint4 v1 = m4[(size_t)ja.y * 16 + t];
        uint4 v2 = m4[(size_t)ja.z * 16 + t];
        uint4 v3 = m4[(size_t)ja.w * 16 + t];
        uint4 v4 = m4[(size_t)jb.x * 16 + t];
        uint4 v5 = m4[(size_t)jb.y * 16 + t];
        uint4 v6 = m4[(size_t)jb.z * 16 + t];
        uint4 v7 = m4[(size_t)jb.w * 16 + t];
        float x0 = 0.f, x1 = 0.f, x2 = 0.f, x3 = 0.f;
        float x4 = 0.f, x5 = 0.f, x6 = 0.f, x7 = 0.f;
        if (W) {
            x0 = dinv[ja.x]; x1 = dinv[ja.y]; x2 = dinv[ja.z]; x3 = dinv[ja.w];
            x4 = dinv[jb.x]; x5 = dinv[jb.y]; x6 = dinv[jb.z]; x7 = dinv[jb.w];
        }
        // ---- adds for batch k (waits only on u/w; v/x stay in flight) ----
        qacc1<W>(acc, u0, w0); qacc1<W>(acc, u1, w1);
        qacc1<W>(acc, u2, w2); qacc1<W>(acc, u3, w3);
        qacc1<W>(acc, u4, w4); qacc1<W>(acc, u5, w5);
        qacc1<W>(acc, u6, w6); qacc1<W>(acc, u7, w7);
        u0 = v0; u1 = v1; u2 = v2; u3 = v3;
        u4 = v4; u5 = v5; u6 = v6; u7 = v7;
        w0 = x0; w1 = x1; w2 = x2; w3 = x3;
        w4 = x4; w5 = x5; w6 = x6; w7 = x7;
    }
    // ---- drain last batch ----
    qacc1<W>(acc, u0, w0); qacc1<W>(acc, u1, w1);
    qacc1<W>(acc, u2, w2); qacc1<W>(acc, u3, w3);
    qacc1<W>(acc, u4, w4); qacc1<W>(acc, u5, w5);
    qacc1<W>(acc, u6, w6); qacc1<W>(acc, u7, w7);
}

// In-block degree sort: rank the block's 16 nodes by (padded) row length desc so
// each wave's 4 quarter-nodes have similar trip counts. Stashes starts/lengths.
__device__ inline int degree_perm(const int* __restrict__ rowstart,
                                  const int* __restrict__ rowlen,
                                  int* lens, int* rs, int* perm, int n) {
    if (threadIdx.x < 16) {
        int nn = blockIdx.x * 16 + threadIdx.x;
        rs[threadIdx.x] = (nn < n) ? rowstart[nn] : 0;
        lens[threadIdx.x] = (nn < n) ? rowlen[nn] : -1;
    }
    __syncthreads();
    if (threadIdx.x < 16) {
        int L = lens[threadIdx.x];
        int r = 0;
#pragma unroll
        for (int j = 0; j < 16; ++j) {
            int Lj = lens[j];
            r += (Lj > L || (Lj == L && j < (int)threadIdx.x)) ? 1 : 0;
        }
        perm[r] = threadIdx.x;
    }
    __syncthreads();
    return perm[threadIdx.x >> 4];
}

// ---------------- fused agg(layer1) + gemm(layer2): m2 = dinv*bf16(relu(agg)+b1)@W2 ----------------
__global__ __launch_bounds__(256) void agg_gemm_kernel(
        const uint4* __restrict__ m4,
        const int* __restrict__ rowstart,
        const int* __restrict__ rowlen,
        const int* __restrict__ csr,
        const float* __restrict__ dinv,
        const float* __restrict__ bias,
        const unsigned short* __restrict__ whi,   // W2 frags
        const unsigned short* __restrict__ wlo,
        uint4* __restrict__ out_m, int n) {
    __shared__ unsigned short hbuf[16][HDIM + 8];   // bf16 h tile (+16B pad)
    __shared__ float cbuf[16][HDIM + 4];            // fp32 C tile (+16B pad)
    __shared__ int lens[16];
    __shared__ int rs[16];
    __shared__ int perm[16];
    int t = threadIdx.x & 15;

    int pnl = degree_perm(rowstart, rowlen, lens, rs, perm, n);
    int node = blockIdx.x * 16 + pnl;

    // ---- agg phase (processes node `pnl`, writes hbuf[pnl]) ----
    unsigned short hv[8] = {0, 0, 0, 0, 0, 0, 0, 0};
    if (node < n) {
        float dd = dinv[node];
        float acc[8];
        uint4 u = m4[(size_t)node * 16 + t];
        acc[0] = dd * bf_lo(u.x); acc[1] = dd * bf_hi(u.x);
        acc[2] = dd * bf_lo(u.y); acc[3] = dd * bf_hi(u.y);
        acc[4] = dd * bf_lo(u.z); acc[5] = dd * bf_hi(u.z);
        acc[6] = dd * bf_lo(u.w); acc[7] = dd * bf_hi(u.w);
        int p0 = rs[pnl];
        qgather<true>(m4, csr, dinv, p0, p0 + lens[pnl], t, acc);
        float4 b0 = *(const float4*)&bias[t * 8];
        float4 b1 = *(const float4*)&bias[t * 8 + 4];
        float bb[8] = {b0.x, b0.y, b0.z, b0.w, b1.x, b1.y, b1.z, b1.w};
#pragma unroll
        for (int j = 0; j < 8; ++j)
            hv[j] = f2bf_rne(fmaxf(fmaf(dd, acc[j], bb[j]), 0.f));
    }
    *(uint4*)&hbuf[pnl][t * 8] = *(uint4*)hv;
    __syncthreads();

    // ---- gemm phase: each wave does 2 column tiles, all 4 kt ----
    int w = threadIdx.x >> 6, L = threadIdx.x & 63;
    int lm = L & 15, lq = L >> 4;
    f32x4 acc2[2];
    acc2[0] = (f32x4)(0.f);
    acc2[1] = (f32x4)(0.f);
#pragma unroll
    for (int kt = 0; kt < 4; ++kt) {
        bfrag a = *(const bfrag*)&hbuf[lm][kt * 32 + lq * 8];
#pragma unroll
        for (int q2 = 0; q2 < 2; ++q2) {
            int nt = w * 2 + q2;
            int o = ((kt * 8 + nt) * 64 + L) * 8;
            bfrag wh = *(const bfrag*)&whi[o];
            bfrag wl = *(const bfrag*)&wlo[o];
            acc2[q2] = __builtin_amdgcn_mfma_f32_16x16x32_bf16(a, wh, acc2[q2], 0, 0, 0);
            acc2[q2] = __builtin_amdgcn_mfma_f32_16x16x32_bf16(a, wl, acc2[q2], 0, 0, 0);
        }
    }
    // C/D layout: col(in tile)=lane&15, row=(lane>>4)*4+i; logical col = lm*8+nt
#pragma unroll
    for (int q2 = 0; q2 < 2; ++q2) {
        int nt = w * 2 + q2;
#pragma unroll
        for (int i = 0; i < 4; ++i) cbuf[lq * 4 + i][lm * 8 + nt] = acc2[q2][i];
    }
    __syncthreads();

    // ---- repack + pre-scale by dinv + round + store (original node order) ----
    int nl = threadIdx.x >> 4;
    int node_e = blockIdx.x * 16 + nl;
    if (node_e < n) {
        float dde = dinv[node_e];
        float4 r0 = *(const float4*)&cbuf[nl][t * 8];
        float4 r1 = *(const float4*)&cbuf[nl][t * 8 + 4];
        unsigned short ev[8];
        ev[0] = f2bf_rne(dde * r0.x); ev[1] = f2bf_rne(dde * r0.y);
        ev[2] = f2bf_rne(dde * r0.z); ev[3] = f2bf_rne(dde * r0.w);
        ev[4] = f2bf_rne(dde * r1.x); ev[5] = f2bf_rne(dde * r1.y);
        ev[6] = f2bf_rne(dde * r1.z); ev[7] = f2bf_rne(dde * r1.w);
        out_m[(size_t)node_e * 16 + t] = *(uint4*)ev;
    }
}

// ---------------- agg layer 2 fused with global max pool ----------------
// m2 rows pre-scaled by dinv[src] -> pure-add gather; degree-sorted waves.
__global__ __launch_bounds__(256) void agg_pool_kernel(const uint4* __restrict__ m4,
                                                       const int* __restrict__ rowstart,
                                                       const int* __restrict__ rowlen,
                                                       const int* __restrict__ csr,
                                                       const float* __restrict__ dinv,
                                                       const float* __restrict__ bias,
                                                       const int* __restrict__ batch,
                                                       unsigned int* __restrict__ g, int n) {
    __shared__ float smx[16][HDIM];
    __shared__ int sgid[16];
    __shared__ int lens[16];
    __shared__ int rs[16];
    __shared__ int perm[16];
    int t = threadIdx.x & 15;

    int pnl = degree_perm(rowstart, rowlen, lens, rs, perm, n);
    int node = blockIdx.x * 16 + pnl;
    bool valid = node < n;
    if (valid) {
        float dd = dinv[node];
        float acc[8];
        uint4 u = m4[(size_t)node * 16 + t];
        acc[0] = bf_lo(u.x); acc[1] = bf_hi(u.x);
        acc[2] = bf_lo(u.y); acc[3] = bf_hi(u.y);
        acc[4] = bf_lo(u.z); acc[5] = bf_hi(u.z);
        acc[6] = bf_lo(u.w); acc[7] = bf_hi(u.w);
        int p0 = rs[pnl];
        qgather<false>(m4, csr, dinv, p0, p0 + lens[pnl], t, acc);
        float4 b0 = *(const float4*)&bias[t * 8];
        float4 b1 = *(const float4*)&bias[t * 8 + 4];
        float4 r0, r1;
        r0.x = fmaxf(fmaf(dd, acc[0], b0.x), 0.f);
        r0.y = fmaxf(fmaf(dd, acc[1], b0.y), 0.f);
        r0.z = fmaxf(fmaf(dd, acc[2], b0.z), 0.f);
        r0.w = fmaxf(fmaf(dd, acc[3], b0.w), 0.f);
        r1.x = fmaxf(fmaf(dd, acc[4], b1.x), 0.f);
        r1.y = fmaxf(fmaf(dd, acc[5], b1.y), 0.f);
        r1.z = fmaxf(fmaf(dd, acc[6], b1.z), 0.f);
        r1.w = fmaxf(fmaf(dd, acc[7], b1.w), 0.f);
        *(float4*)&smx[pnl][t * 8] = r0;
        *(float4*)&smx[pnl][t * 8 + 4] = r1;
    }
    if (t == 0) sgid[pnl] = valid ? batch[node] : -1;
    __syncthreads();
    // smx/sgid indexed by original node order -> batch runs stay contiguous.
    if (threadIdx.x < HDIM) {
        int c = threadIdx.x;
        int curg = -1;
        float run = 0.f;
#pragma unroll
        for (int r = 0; r < 16; ++r) {
            int gg = sgid[r];
            if (gg < 0) continue;
            if (gg != curg) {
                if (curg >= 0) atomicMax(&g[curg * HDIM + c], __float_as_uint(run));
                curg = gg;
                run = smx[r][c];
            } else {
                run = fmaxf(run, smx[r][c]);
            }
        }
        if (curg >= 0) atomicMax(&g[curg * HDIM + c], __float_as_uint(run));
    }
}

// ---------------- MLP head + log_softmax ----------------
__global__ __launch_bounds__(128) void mlp_kernel(const unsigned int* __restrict__ gbits,
                                                  const float* __restrict__ W3,
                                                  const float* __restrict__ b3,
                                                  const float* __restrict__ W4,
                                                  const float* __restrict__ b4,
                                                  float* __restrict__ out) {
    __shared__ float gs[HDIM];
    __shared__ float r0[HDIM];
    __shared__ float r1[HDIM];
    int j = threadIdx.x;
    int b = blockIdx.x;
    gs[j] = __uint_as_float(gbits[b * HDIM + j]);
    __syncthreads();
    float acc = b3[j];
#pragma unroll 8
    for (int k = 0; k < HDIM; ++k) acc = fmaf(gs[k], W3[k * HDIM + j], acc);
    float z = fmaxf(acc, 0.f);
    r0[j] = z * W4[j * 2 + 0];
    r1[j] = z * W4[j * 2 + 1];
    __syncthreads();
    for (int off = 64; off > 0; off >>= 1) {
        if (j < off) {
            r0[j] += r0[j + off];
            r1[j] += r1[j + off];
        }
        __syncthreads();
    }
    if (j == 0) {
        float l0 = r0[0] + b4[0];
        float l1 = r1[0] + b4[1];
        float mx = fmaxf(l0, l1);
        float lse = mx + logf(expf(l0 - mx) + expf(l1 - mx));
        out[b * 2 + 0] = l0 - lse;
        out[b * 2 + 1] = l1 - lse;
    }
}

extern "C" void kernel_launch(void* const* d_in, const int* in_sizes, int n_in,
                              void* d_out, int out_size, void* d_ws, size_t ws_size,
                              hipStream_t stream) {
    const float* x  = (const float*)d_in[0];
    const float* W1 = (const float*)d_in[1];
    const float* b1 = (const float*)d_in[2];
    const float* W2 = (const float*)d_in[3];
    const float* b2 = (const float*)d_in[4];
    const float* W3 = (const float*)d_in[5];
    const float* b3 = (const float*)d_in[6];
    const float* W4 = (const float*)d_in[7];
    const float* b4 = (const float*)d_in[8];
    const int* ei    = (const int*)d_in[9];
    const int* batch = (const int*)d_in[10];

    const int N = in_sizes[0] / HDIM;   // 50000
    const int E = in_sizes[9] / 2;      // 640000
    const int G = out_size / 2;         // 64
    const int* src = ei;
    const int* dst = ei + E;

    const int nbuck = (N + 255) >> 8;        // 196 (must be <= 256)
    const int nscan = nbuck * NBLK;          // 50176
    const int chunk = (E + NBLK - 1) / NBLK; // 2500

    // ---- workspace layout (16B-aligned blocks) ----
    const int Nr = ((N + 63) / 64) * 64;
    char* wsb = (char*)d_ws;
    size_t o = 0;
    unsigned int* g = (unsigned int*)(wsb + o); o += (size_t)G * HDIM * 4;
    size_t zero_bytes = o;                 // only g needs zeroing
    int* hist = (int*)(wsb + o);           o += (size_t)nscan * 4;
    int* hscan = (int*)(wsb + o);          o += (size_t)nscan * 4;
    int* sums = (int*)(wsb + o);           o += 256 * 4;
    int* rowstart = (int*)(wsb + o);       o += (size_t)(Nr + 64) * 4;
    int* rowlen = (int*)(wsb + o);         o += (size_t)(Nr + 64) * 4;
    float* dinv = (float*)(wsb + o);       o += (size_t)Nr * 4;
    int2* sorted = (int2*)(wsb + o);       o += (size_t)E * 8;
    int* csr = (int*)(wsb + o);            o += ((size_t)E + (size_t)nbuck * BPAD + 2048) * 4;
    unsigned short* wf1h = (unsigned short*)(wsb + o); o += (size_t)HDIM * HDIM * 2;
    unsigned short* wf1l = (unsigned short*)(wsb + o); o += (size_t)HDIM * HDIM * 2;
    unsigned short* wf2h = (unsigned short*)(wsb + o); o += (size_t)HDIM * HDIM * 2;
    unsigned short* wf2l = (unsigned short*)(wsb + o); o += (size_t)HDIM * HDIM * 2;
    unsigned short* m = (unsigned short*)(wsb + o);    o += (size_t)(Nr + 64) * HDIM * 2;
    unsigned short* m2 = (unsigned short*)(wsb + o);   o += (size_t)(Nr + 64) * HDIM * 2;
    (void)ws_size; (void)n_in;

    (void)hipMemsetAsync(d_ws, 0, zero_bytes, stream);

    int sblocks = (nscan + SCAN_B - 1) / SCAN_B;   // 196 (<= 256 required)
    int gemm_blocks = (N + GBM - 1) / GBM;         // 782
    int agg_blocks = (N + 15) / 16;                // 3125

    // K1: hist || wfrag  (independent)
    mega1_kernel<<<NBLK + 128, 256, 0, stream>>>(dst, hist, E, chunk, nbuck,
                                                 W1, W2, wf1h, wf1l, wf2h, wf2l);
    // K2: scan of hist matrix (bucket-major) -> hscan exclusive (2 dispatches);
    //     scan3 block 0 also zeroes dummy row N of m/m2 and dinv[N]
    scan1_kernel<<<sblocks, SCAN_B, 0, stream>>>(hist, hscan, sums, nscan);
    scan3_kernel<<<sblocks, SCAN_B, 0, stream>>>(hist, hscan, sums, nscan, m, m2, dinv, N);
    // K3: scatter (bucket sort) || gemm layer 1
    mega3_kernel<<<NBLK + gemm_blocks, 256, 0, stream>>>(src, dst, hscan, sorted,
                                                         E, chunk, nbuck,
                                                         x, wf1h, wf1l, m, N);
    // K4: per-bucket PADDED CSR build (rowstart, rowlen, dinv, csr)
    csr_kernel<<<nbuck, 256, 0, stream>>>(sorted, hscan, rowstart, rowlen, dinv, csr,
                                          N, E, nbuck);
    // K5: fused agg(layer1) + gemm(layer2) -> m2 (dinv-pre-scaled)
    agg_gemm_kernel<<<agg_blocks, 256, 0, stream>>>((const uint4*)m, rowstart, rowlen,
                                                    csr, dinv, b1, wf2h, wf2l,
                                                    (uint4*)m2, N);
    // K6: agg layer 2 + global max pool
    agg_pool_kernel<<<agg_blocks, 256, 0, stream>>>((const uint4*)m2, rowstart, rowlen,
                                                    csr, dinv, b2, batch, g, N);
    // K7: MLP head + log_softmax
    mlp_kernel<<<G, 128, 0, stream>>>(g, W3, b3, W4, b4, (float*)d_out);
}